// Round 9
// baseline (183.546 us; speedup 1.0000x reference)
//
#include <hip/hip_runtime.h>
#include <hip/hip_bf16.h>
#include <hip/hip_cooperative_groups.h>
#include <math.h>

namespace cg = cooperative_groups;

// Problem constants
constexpr int NSAMP  = 131072;
constexpr int NEV    = 128;
constexpr int ASIZE  = 512;
constexpr int LDIM   = 16;
constexpr int NLAYER = 7;
constexpr int NFFT   = 393216;     // padded FFT length (3*NSAMP)
constexpr int MHALF  = 196608;     // NFFT/2
constexpr double TWO_PI = 6.283185307179586;

// Pipeline: f32-faithful front-end (bit-exact bt -> s), f32-quantized phases
// theta = f32(f32(2k*pi_f32)/196609f * s) [the ghost field], f32 spectra
// partials, inverse real FFT = radix-3 split x (256x256 four-step, ALL f32).
// Forward: k = b + 768a, S_e(b+768a) = FFT512_a{ z_e[u]*T_b[u] }; Hermitian
// trick -> b in [0,384]. FFT-512 = 3 in-place radix-8 stages, wave-private,
// register-staged.
// R15 = R14 + inv_a/inv_b FUSED into one cooperative kernel (grid.sync() at
// the Yg transpose). Calibration from R13->R14: one kernel slot (launch +
// gap + drain) ~4-5 us. Geometry: 256 blocks x 192 threads (3 waves, 12 KB
// LDS) = 1 block/CU -> trivially co-resident. Phase A: wave w of block blk
// runs the EXACT inv_a body for (l=w, j1=blk) in its own 4 KB LDS slice
// (barrier-free, single wave). Phase B: exact inv_b body (block = m1).
// All value chains bit-identical to R14 (absmax 2.384e-07).

__device__ __forceinline__ float2 cmulf(float2 a, float2 b) {
    return make_float2(a.x*b.x - a.y*b.y, a.x*b.y + a.y*b.x);
}
__device__ __forceinline__ float2 CADD(float2 a, float2 b){ return make_float2(a.x+b.x, a.y+b.y); }
__device__ __forceinline__ float2 CSUB(float2 a, float2 b){ return make_float2(a.x-b.x, a.y-b.y); }

// sin/cos of the EXACT value of a float32 phase (magnitude up to ~8e5):
// exact mod-2pi reduction in double via two fmas, then fast f32 sincos.
__device__ __forceinline__ void phase_sc(float th32, float* ps, float* pc) {
    const double th = (double)th32;
    const double n  = rint(th * 0.15915494309189535);
    double r = fma(-n, 6.283185307179586, th);
    r = fma(-n, 2.4492935982947064e-16, r);
    __sincosf((float)r, ps, pc);
}

// forward DFT-8 on registers (verified, R8)
#define RT2 0.70710678118654752f
#define DFT8F(A0,A1,A2,A3,A4,A5,A6,A7, X0,X1,X2,X3,X4,X5,X6,X7) { \
  float2 b0=CADD(A0,A4), b1=CADD(A1,A5), b2=CADD(A2,A6), b3=CADD(A3,A7); \
  float2 c0=CSUB(A0,A4); \
  float2 d1=CSUB(A1,A5), d2=CSUB(A2,A6), d3=CSUB(A3,A7); \
  float2 c1=make_float2((d1.x+d1.y)*RT2, (d1.y-d1.x)*RT2); \
  float2 c2=make_float2(d2.y, -d2.x); \
  float2 c3=make_float2((d3.y-d3.x)*RT2, -(d3.x+d3.y)*RT2); \
  float2 t0=CADD(b0,b2), t1=CSUB(b0,b2), t2=CADD(b1,b3), t3=CSUB(b1,b3); \
  X0=CADD(t0,t2); X4=CSUB(t0,t2); \
  X2=make_float2(t1.x+t3.y, t1.y-t3.x); X6=make_float2(t1.x-t3.y, t1.y+t3.x); \
  t0=CADD(c0,c2); t1=CSUB(c0,c2); t2=CADD(c1,c3); t3=CSUB(c1,c3); \
  X1=CADD(t0,t2); X5=CSUB(t0,t2); \
  X3=make_float2(t1.x+t3.y, t1.y-t3.x); X7=make_float2(t1.x-t3.y, t1.y+t3.x); \
}

// ---------------------------------------------------------------------------
// K1 (merged): blocks 0..384: Ttab row b (lane-transposed for K3).
// Block 385: Twf + Tk + Tm tables (read only by LATER launches).
// Blocks 386..513: event e = blk-386 — recompute own latent/offset ancestor
// chain (bit-identical op sequence), then mix->window(inline)->norm->amp,
// store lane-transposed zf and sF[e]. No intra-launch dependencies.
// ---------------------------------------------------------------------------
__global__ __launch_bounds__(256) void init_events(
    const float* __restrict__ base, const float* __restrict__ to_off_w,
    const float* __restrict__ split_w, const float* __restrict__ split_b,
    const float* __restrict__ atoms, const float* __restrict__ to_atoms_w,
    const float* __restrict__ to_atoms_b, const float* __restrict__ to_amp_w,
    const float* __restrict__ to_amp_b,
    float* __restrict__ sF, float2* __restrict__ Twf,
    float2* __restrict__ Ttab,
    float2* __restrict__ Tk, float2* __restrict__ Tm,
    float* __restrict__ zf)
{
    const int blk = blockIdx.x;
    const int tid = threadIdx.x;
    if (blk < 385) {
        const int b = blk;                       // 0..384
        for (int j = tid; j < 512; j += 256) {
            double s, c;
            sincos(-TWO_PI*(double)(b*j)/(double)NFFT, &s, &c);
            Ttab[b*512 + (j & 63)*8 + (j >> 6)] = make_float2((float)c, (float)s);
        }
        return;
    }
    if (blk == 385) {
        double s, c;
        sincos(TWO_PI*(double)tid/256.0,   &s, &c); Twf[tid]       = make_float2((float)c,(float)s);
        sincos(TWO_PI*(double)tid/512.0,   &s, &c); Twf[256 + tid] = make_float2((float)c,(float)s);
        sincos(TWO_PI*(double)tid/768.0,   &s, &c); Twf[512 + tid] = make_float2((float)c,(float)s);
        sincos(TWO_PI*(double)tid/65536.0, &s, &c); Twf[768 + tid] = make_float2((float)c,(float)s);
        // inv_a twiddle: e^{2pi i k0/NFFT}, k0 in [0,768)
        for (int k0 = tid; k0 < 768; k0 += 256) {
            sincos(TWO_PI*(double)k0/(double)NFFT, &s, &c);
            Tk[k0] = make_float2((float)c, (float)s);
        }
        // inv_b twiddle: e^{2pi i m1/MHALF}, m1 in [0,256)
        {
            sincos(TWO_PI*(double)tid/(double)MHALF, &s, &c);
            Tm[tid] = make_float2((float)c, (float)s);
        }
        return;
    }

    // ---- event block: e = blk - 386 ----
    const int e = blk - 386;
    __shared__ float xcur[LDIM], xnxt[LDIM];
    __shared__ float btS;
    __shared__ float mixS[32];
    __shared__ float evS[ASIZE];
    __shared__ double red[256];
    __shared__ float scl[2];

    // recompute latent/offset ancestor chain (bit-identical op sequence)
    if (tid < LDIM) xcur[tid] = base[tid];
    if (tid == 0) btS = 0.0f;
    __syncthreads();
    for (int i = 0; i < NLAYER; ++i) {
        const int j = (e >> (6 - i)) & 1;
        const float scale = 1.0f / (float)(1 << i);
        if (tid < LDIM) {
            const float* wr = split_w + (i*32 + j*16 + tid)*LDIM;
            float s = __fmul_rn(xcur[0], wr[0]);
            for (int l = 1; l < LDIM; ++l)
                s = __fadd_rn(s, __fmul_rn(xcur[l], wr[l]));
            s = __fadd_rn(s, split_b[i*32 + j*16 + tid]);
            xnxt[tid] = s;
        }
        if (tid == 64) {       // other wave: offset chain (reads xcur only)
            const float* wr = to_off_w + (i*2 + j)*LDIM;
            float v = __fmul_rn(xcur[0], wr[0]);
            for (int l = 1; l < LDIM; ++l)
                v = __fadd_rn(v, __fmul_rn(xcur[l], wr[l]));
            const float ef = (float)exp(-(double)v);
            const float sg = __fdiv_rn(1.0f, __fadd_rn(1.0f, ef));
            btS = __fadd_rn(btS, __fmul_rn(sg, scale));
        }
        __syncthreads();
        if (tid < LDIM) xcur[tid] = xnxt[tid];
        __syncthreads();
    }
    if (tid == 0)
        sF[e] = __fmul_rn(__fmul_rn(btS, 131072.0f), 0.5f);

    // mix -> window(inline, bit-identical) -> norm -> amp (strict f32 chain)
    if (tid < 32) {
        const float* wr = to_atoms_w + tid*LDIM;
        float m = __fmul_rn(xcur[0], wr[0]);
        for (int l = 1; l < LDIM; ++l) m = __fadd_rn(m, __fmul_rn(xcur[l], wr[l]));
        mixS[tid] = __fadd_rn(m, to_atoms_b[tid]);
    }
    __syncthreads();
    double ss = 0.0;
    for (int u = tid; u < ASIZE; u += 256) {
        float v = __fmul_rn(mixS[0], atoms[u]);
        for (int a = 1; a < 32; ++a)
            v = __fadd_rn(v, __fmul_rn(mixS[a], atoms[a*ASIZE + u]));
        const float ang = __fdiv_rn(__fmul_rn(6.283185307179586f, (float)u), 512.0f);
        const float cw = (float)cos((double)ang);
        const float w  = __fsub_rn(0.54f, __fmul_rn(0.46f, cw));
        v = __fmul_rn(v, w);
        evS[u] = v;
        ss += (double)v * (double)v;
    }
    red[tid] = ss; __syncthreads();
    for (int s = 128; s > 0; s >>= 1) { if (tid < s) red[tid] += red[tid+s]; __syncthreads(); }
    if (tid == 0) {
        const float nf = (float)sqrt(red[0]);
        scl[0] = __fadd_rn(nf, 1e-8f);
        float a = __fmul_rn(xcur[0], to_amp_w[0]);
        for (int l = 1; l < LDIM; ++l) a = __fadd_rn(a, __fmul_rn(xcur[l], to_amp_w[l]));
        scl[1] = __fadd_rn(a, to_amp_b[0]);
    }
    __syncthreads();
    const float den = scl[0], amp = scl[1];
    for (int u = tid; u < ASIZE; u += 256)
        zf[e*ASIZE + (u & 63)*8 + (u >> 6)] =
            __fmul_rn(__fdiv_rn(evS[u], den), amp);
}

// ---------------------------------------------------------------------------
// K3 (hot): forward, in-place radix-8^3 FFT-512 per wave (R10-exact, 48 us).
// T row in registers (loop-invariant), z via 2x dwordx4 + software pipeline,
// se from sF per-iteration. Launch bound (256,3): R9's (256,4) forced spills;
// R11's in-register twiddle powers regressed (compiler remat'd sincosf).
// ---------------------------------------------------------------------------
__global__ __launch_bounds__(256, 3) void forward_v3(
    const float* __restrict__ zf, const float* __restrict__ sF,
    const float2* __restrict__ Ttab, float* __restrict__ Hqf)
{
    __shared__ float2 FB[4*576];        // 18432 B wave-private padded buffers
    const int b       = blockIdx.x >> 2;     // 0..384
    const int quarter = blockIdx.x & 3;
    const int tid  = threadIdx.x;
    const int wave = tid >> 6, lane = tid & 63;
    float2* F = FB + wave*576;
    const int e0 = quarter*32;

    // T row -> 8 float2 registers (lane-transposed layout, 4x dwordx4, once)
    const float4* Tg4 = (const float4*)(Ttab + b*512 + lane*8);
    const float4 tA = Tg4[0], tB = Tg4[1], tC = Tg4[2], tD = Tg4[3];
    const float2 T0 = make_float2(tA.x, tA.y), T1 = make_float2(tA.z, tA.w);
    const float2 T2 = make_float2(tB.x, tB.y), T3 = make_float2(tB.z, tB.w);
    const float2 T4 = make_float2(tC.x, tC.y), T5 = make_float2(tC.z, tC.w);
    const float2 T6 = make_float2(tD.x, tD.y), T7 = make_float2(tD.z, tD.w);

    // register twiddle bases (FFT-internal; slop-tolerant)
    float2 w0b, w1b;
    __sincosf(-6.283185307179586f/512.0f * (float)lane,        &w0b.y, &w0b.x);
    __sincosf(-6.283185307179586f/64.0f  * (float)(lane >> 3), &w1b.y, &w1b.x);

    // f32 phase coefficient chains (bit-identical to np)
    float c2a[4], c2b[4];
    #pragma unroll
    for (int j = 0; j < 4; ++j) {
        const int a  = lane + 64*j;
        const int k1 = b + 768*a;
        const int k2 = (768 - b) + 768*(255 - a);
        c2a[j] = __fdiv_rn(__fmul_rn((float)(2*k1), 3.14159274101257324f), 196609.0f);
        c2b[j] = __fdiv_rn(__fmul_rn((float)(2*k2), 3.14159274101257324f), 196609.0f);
    }

    float a1R[4]={0,0,0,0}, a1I[4]={0,0,0,0};
    float a2R[4]={0,0,0,0}, a2I[4]={0,0,0,0};
    const int ph = lane + (lane >> 3);        // padded read base

    // z pipeline: lane-transposed layout, 2x dwordx4 per event; stride
    // between events = 512 floats = 128 float4.
    const float4* zp4 = (const float4*)(zf + (e0 + wave*8)*ASIZE + lane*8);
    float4 za = zp4[0], zb = zp4[1];

    for (int it = 0; it < 8; ++it) {
        const float sev = sF[e0 + wave*8 + it];   // wave-uniform scalar load
        // ---- stage 0 (st=1, p=lane): inputs z*T in registers
        {
            const float2 i0 = make_float2(za.x*T0.x, za.x*T0.y);
            const float2 i1 = make_float2(za.y*T1.x, za.y*T1.y);
            const float2 i2 = make_float2(za.z*T2.x, za.z*T2.y);
            const float2 i3 = make_float2(za.w*T3.x, za.w*T3.y);
            const float2 i4 = make_float2(zb.x*T4.x, zb.x*T4.y);
            const float2 i5 = make_float2(zb.y*T5.x, zb.y*T5.y);
            const float2 i6 = make_float2(zb.z*T6.x, zb.z*T6.y);
            const float2 i7 = make_float2(zb.w*T7.x, zb.w*T7.y);
            // prefetch next event's z (values consumed above). At it=7 this
            // reads 64B past zf, which is the (allocated) Ttab region — safe,
            // value unused.
            za = zp4[(it+1)*128];
            zb = zp4[(it+1)*128 + 1];
            float2 x0,x1,x2,x3,x4,x5,x6,x7;
            DFT8F(i0,i1,i2,i3,i4,i5,i6,i7, x0,x1,x2,x3,x4,x5,x6,x7);
            const int ob = 9*lane;                 // phys(8p+m) = 9p+m
            float2 wm = w0b;
            F[ob]   = x0;
            F[ob+1] = cmulf(x1, wm); wm = cmulf(wm, w0b);
            F[ob+2] = cmulf(x2, wm); wm = cmulf(wm, w0b);
            F[ob+3] = cmulf(x3, wm); wm = cmulf(wm, w0b);
            F[ob+4] = cmulf(x4, wm); wm = cmulf(wm, w0b);
            F[ob+5] = cmulf(x5, wm); wm = cmulf(wm, w0b);
            F[ob+6] = cmulf(x6, wm); wm = cmulf(wm, w0b);
            F[ob+7] = cmulf(x7, wm);
        }
        // ---- stage 1 (st=8): in-place (whole-wave reads precede writes)
        {
            const float2 i0 = F[ph      ], i1 = F[ph +  72], i2 = F[ph + 144],
                         i3 = F[ph + 216], i4 = F[ph + 288], i5 = F[ph + 360],
                         i6 = F[ph + 432], i7 = F[ph + 504];
            float2 x0,x1,x2,x3,x4,x5,x6,x7;
            DFT8F(i0,i1,i2,i3,i4,i5,i6,i7, x0,x1,x2,x3,x4,x5,x6,x7);
            const int q = lane & 7, p = lane >> 3;
            const int ob = q + 72*p;               // phys(q+64p+8m) = q+72p+9m
            float2 wm = w1b;
            F[ob]    = x0;
            F[ob+ 9] = cmulf(x1, wm); wm = cmulf(wm, w1b);
            F[ob+18] = cmulf(x2, wm); wm = cmulf(wm, w1b);
            F[ob+27] = cmulf(x3, wm); wm = cmulf(wm, w1b);
            F[ob+36] = cmulf(x4, wm); wm = cmulf(wm, w1b);
            F[ob+45] = cmulf(x5, wm); wm = cmulf(wm, w1b);
            F[ob+54] = cmulf(x6, wm); wm = cmulf(wm, w1b);
            F[ob+63] = cmulf(x7, wm);
        }
        // ---- stage 2 (st=64, p=0): outputs in registers, Y[m] = bin(lane+64m)
        float2 Y[8];
        {
            const float2 i0 = F[ph      ], i1 = F[ph +  72], i2 = F[ph + 144],
                         i3 = F[ph + 216], i4 = F[ph + 288], i5 = F[ph + 360],
                         i6 = F[ph + 432], i7 = F[ph + 504];
            DFT8F(i0,i1,i2,i3,i4,i5,i6,i7, Y[0],Y[1],Y[2],Y[3],Y[4],Y[5],Y[6],Y[7]);
        }
        // ---- accumulate
        #pragma unroll
        for (int j = 0; j < 4; ++j) {
            float ps, pc;
            const float2 S0 = Y[j];
            phase_sc(__fmul_rn(c2a[j], sev), &ps, &pc);
            a1R[j] = fmaf(S0.x, pc, fmaf(-S0.y, ps, a1R[j]));
            a1I[j] = fmaf(S0.x, ps, fmaf( S0.y, pc, a1I[j]));
            const float2 S1 = Y[j+4];   // conj(S1) * e^{i theta}
            phase_sc(__fmul_rn(c2b[j], sev), &ps, &pc);
            a2R[j] = fmaf(S1.x, pc, fmaf( S1.y, ps, a2R[j]));
            a2I[j] = fmaf(S1.x, ps, fmaf(-S1.y, pc, a2I[j]));
        }
    }

    // ---- cross-wave reduction (2 rounds in the FFT region) + stores
    float* redF = (float*)FB;
    #pragma unroll
    for (int round = 0; round < 2; ++round) {
        __syncthreads();
        const int j0 = 2*round;
        float* my = redF + (wave*64 + lane)*8;
        my[0]=a1R[j0];   my[1]=a1I[j0];   my[2]=a2R[j0];   my[3]=a2I[j0];
        my[4]=a1R[j0+1]; my[5]=a1I[j0+1]; my[6]=a2R[j0+1]; my[7]=a2I[j0+1];
        __syncthreads();
        const int s = tid >> 2, c = tid & 3;
        #pragma unroll
        for (int jr = 0; jr < 2; ++jr) {
            float v = 0.f;
            #pragma unroll
            for (int w = 0; w < 4; ++w) v += redF[(w*64 + s)*8 + jr*4 + c];
            const int as = s + 64*(j0 + jr);
            if (c < 2) {
                Hqf[2*(quarter*196609 + b*256 + as) + c] = v;
            } else if (b != 384) {
                if (b != 0)
                    Hqf[2*(quarter*196609 + (768-b)*256 + (255-as)) + (c-2)] = v;
                else if (as == 0)
                    Hqf[2*(quarter*196609 + 196608) + (c-2)] = v;
            }
        }
    }
}

// ---------------------------------------------------------------------------
// inverse radix-4 Stockham stage over 256 points, 64 threads, f32, table
// twiddles (w = e^{+2pi i p*st/256} = Tw256f[p*st]; math verified R6-R8).
// ---------------------------------------------------------------------------
__device__ __forceinline__ void ifft256f_stage(
    const float2* __restrict__ src, float2* __restrict__ dst, int t, int s4,
    const float2* __restrict__ Tw256f)
{
    const int lg = 2*s4, st = 1 << lg;
    const int q = t & (st-1), p = t >> lg;
    const float2 A0 = src[t], A1 = src[t+64], A2 = src[t+128], A3 = src[t+192];
    const float Pr = A0.x + A2.x, Pi_ = A0.y + A2.y;
    const float Qr = A0.x - A2.x, Qi  = A0.y - A2.y;
    const float Rr = A1.x + A3.x, Ri  = A1.y + A3.y;
    const float Sr = A1.x - A3.x, Si  = A1.y - A3.y;
    const int tw = p*st;
    const float2 w1 = Tw256f[tw];
    const float2 w2 = Tw256f[(2*tw) & 255];
    const float2 w3 = Tw256f[(3*tw) & 255];
    const int o = q + 4*st*p;
    dst[o] = make_float2(Pr + Rr, Pi_ + Ri);
    const float u1r = Qr - Si, u1i = Qi + Sr;
    dst[o + st]   = make_float2(u1r*w1.x - u1i*w1.y, u1r*w1.y + u1i*w1.x);
    const float u2r = Pr - Rr, u2i = Pi_ - Ri;
    dst[o + 2*st] = make_float2(u2r*w2.x - u2i*w2.y, u2r*w2.y + u2i*w2.x);
    const float u3r = Qr + Si, u3i = Qi - Sr;
    dst[o + 3*st] = make_float2(u3r*w3.x - u3i*w3.y, u3r*w3.y + u3i*w3.x);
}

// ---------------------------------------------------------------------------
// K4+K5 fused (cooperative): phase A = 768 single-wave jobs (wave w of block
// blk handles l=w, j1=blk — exact inv_a body, barrier-free, own 4KB LDS
// slice); grid.sync(); phase B = exact inv_b body (block = m1).
// 256 blocks x 192 threads, 12 KB LDS -> 1 block/CU, co-resident.
// ---------------------------------------------------------------------------
__global__ __launch_bounds__(192) void inv_fused(
    const float* __restrict__ Hqf, const float2* __restrict__ Twf,
    const float2* __restrict__ Tk, const float2* __restrict__ Tm,
    float2* __restrict__ Yg, float* __restrict__ out)
{
    __shared__ float2 buf[3*512];
    const int tid = threadIdx.x;
    const int l = tid >> 6, t = tid & 63;
    const float2* Tw256f = Twf;
    const float2* Tw512f = Twf + 256;
    const float2* Tw768f = Twf + 512;
    const float2* Tw64kf = Twf + 768;

    // ================= phase A (inv_a body; wave-private) =================
    {
        const int j1 = blockIdx.x;              // 0..255
        const int k0 = 3*j1 + l;
        float2* A = buf + l*512;
        float2* B = A + 256;
        const float2* Hq2 = (const float2*)Hqf;

        const float2 tkv = Tk[k0];              // e^{2pi i k0/NFFT}
        const float Scf = tkv.x, Ssf = tkv.y;

        #pragma unroll
        for (int r = 0; r < 4; ++r) {
            const int j2 = t + 64*r;
            const int idxK = k0*256 + j2;
            int idxM;
            if (k0 > 0) idxM = (768 - k0)*256 + (255 - j2);
            else        idxM = (j2 == 0) ? 196608 : (256 - j2);
            float hkR=0.f, hkI=0.f, hmR=0.f, hmI=0.f;
            #pragma unroll
            for (int q = 0; q < 4; ++q) {
                const float2 vk = Hq2[q*196609 + idxK];
                const float2 vm = Hq2[q*196609 + idxM];
                hkR += vk.x; hkI += vk.y;
                hmR += vm.x; hmI += vm.y;
            }
            if (k0 == 0 && j2 == 0) { hkI = 0.f; hmI = 0.f; }  // irfft Im-drop
            const float Pr = hkR + hmR, Pi_ = hkI - hmI;
            const float Qr = hkR - hmR, Qi = hkI + hmI;
            const float2 t5 = Tw512f[j2];                  // e^{2pi i j2/512}
            const float Wc = Scf*t5.x - Ssf*t5.y;          // e^{2pi i k/NFFT}
            const float Wsn = Scf*t5.y + Ssf*t5.x;
            const float WQr = Wc*Qr - Wsn*Qi;
            const float WQi = Wc*Qi + Wsn*Qr;
            A[j2] = make_float2(0.5f*(Pr - WQi), 0.5f*(Pi_ + WQr));
        }

        ifft256f_stage(A, B, t, 0, Tw256f);
        ifft256f_stage(B, A, t, 1, Tw256f);
        ifft256f_stage(A, B, t, 2, Tw256f);
        ifft256f_stage(B, A, t, 3, Tw256f);

        #pragma unroll
        for (int r = 0; r < 4; ++r) {
            const int m1 = t + 64*r;
            const float2 v = A[m1];
            const int vv = j1*m1;
            const float2 wa = Tw256f[vv >> 8];
            const float2 wb = Tw64kf[vv & 255];
            const float twc = wa.x*wb.x - wa.y*wb.y;
            const float tws = wa.x*wb.y + wa.y*wb.x;
            Yg[m1*768 + l*256 + j1] =
                make_float2(v.x*twc - v.y*tws, v.x*tws + v.y*twc);
        }
    }

    // ============ grid-wide barrier (Yg transpose visibility) ============
    cg::this_grid().sync();

    // ================= phase B (inv_b body; block = m1) =================
    const int m1 = blockIdx.x;
    {
        float2* A = buf + l*512;
        float2* B = A + 256;
        #pragma unroll
        for (int r = 0; r < 4; ++r) {
            const int j1 = t + 64*r;
            A[j1] = Yg[m1*768 + l*256 + j1];      // coalesced
        }
        ifft256f_stage(A, B, t, 0, Tw256f);
        ifft256f_stage(B, A, t, 1, Tw256f);
        ifft256f_stage(A, B, t, 2, Tw256f);
        ifft256f_stage(B, A, t, 3, Tw256f);
    }
    __syncthreads();

    const float2 tmv = Tm[m1];                    // e^{2pi i m1/MHALF}
    const float cm = tmv.x, sm = tmv.y;
    const float inv = 1.0f/(float)MHALF;
    for (int m2 = tid; m2 < 256; m2 += 192) {
        const float2 F0 = buf[m2];
        const float2 F1 = buf[512 + m2];
        const float2 F2 = buf[1024 + m2];
        const float2 t7 = Tw768f[m2];                 // e^{2pi i m2/768}
        const float w1c = cm*t7.x - sm*t7.y, w1s = cm*t7.y + sm*t7.x;
        const float w2c = w1c*w1c - w1s*w1s, w2s = 2.0f*w1c*w1s;
        const float gr = F0.x + (w1c*F1.x - w1s*F1.y) + (w2c*F2.x - w2s*F2.y);
        const float gi = F0.y + (w1c*F1.y + w1s*F1.x) + (w2c*F2.y + w2s*F2.x);
        const int m = m1 + 256*m2;
        out[2*m]     = gr*inv;
        out[2*m + 1] = gi*inv;
    }
}

// ---------------------------------------------------------------------------
extern "C" void kernel_launch(void* const* d_in, const int* in_sizes, int n_in,
                              void* d_out, int out_size, void* d_ws, size_t ws_size,
                              hipStream_t stream) {
    const float* base       = (const float*)d_in[0];
    const float* to_off_w   = (const float*)d_in[1];
    const float* split_w    = (const float*)d_in[2];
    const float* split_b    = (const float*)d_in[3];
    const float* atoms      = (const float*)d_in[4];
    const float* to_atoms_w = (const float*)d_in[5];
    const float* to_atoms_b = (const float*)d_in[6];
    const float* to_amp_w   = (const float*)d_in[7];
    const float* to_amp_b   = (const float*)d_in[8];
    float* out = (float*)d_out;

    // workspace layout: 8,147,488 B (< 9,715,728 proven-safe in R4).
    // Yg aliases Ttab: forward (last Ttab reader) completes before inv_fused.
    // Tk/Tm live in the old xF slot [8704, 16896).
    // NOTE: forward_v3's z-prefetch at it=7 reads 64B past zf, landing in
    // Ttab — allocated memory, value unused.
    char* ws = (char*)d_ws;
    float2* Twf  = (float2*)(ws + 0);          // 4*256*8 = 8192
    float*  sF   = (float*)(ws + 8192);        //   512
    float2* Tk   = (float2*)(ws + 8704);       // 768*8 = 6144 -> 14848
    float2* Tm   = (float2*)(ws + 14848);      // 256*8 = 2048 -> 16896
    float*  zf   = (float*)(ws + 16896);       // 262144 -> 279040
    float2* Ttab = (float2*)(ws + 279040);     // 385*512*8 = 1576960 -> 1856000
    float2* Yg   = (float2*)(ws + 279040);     // 768*256*8 = 1572864 (alias)
    float*  Hqf  = (float*)(ws + 1856000);     // 4*196609*8 = 6291488 -> 8147488

    init_events<<<514, 256, 0, stream>>>(base, to_off_w, split_w, split_b,
                                         atoms, to_atoms_w, to_atoms_b,
                                         to_amp_w, to_amp_b,
                                         sF, Twf, Ttab, Tk, Tm, zf);
    forward_v3<<<385*4, 256, 0, stream>>>(zf, sF, Ttab, Hqf);

    void* invArgs[] = { (void*)&Hqf, (void*)&Twf, (void*)&Tk, (void*)&Tm,
                        (void*)&Yg, (void*)&out };
    hipLaunchCooperativeKernel((void*)inv_fused, dim3(256), dim3(192),
                               invArgs, 0, stream);
}

// Round 10
// 132.512 us; speedup vs baseline: 1.3851x; 1.3851x over previous
//
#include <hip/hip_runtime.h>
#include <hip/hip_bf16.h>
#include <math.h>

// Problem constants
constexpr int NSAMP  = 131072;
constexpr int NEV    = 128;
constexpr int ASIZE  = 512;
constexpr int LDIM   = 16;
constexpr int NLAYER = 7;
constexpr int NFFT   = 393216;     // padded FFT length (3*NSAMP)
constexpr int MHALF  = 196608;     // NFFT/2
constexpr double TWO_PI = 6.283185307179586;

// Pipeline: f32-faithful front-end (bit-exact bt -> s), f32-quantized phases
// theta = f32(f32(2k*pi_f32)/196609f * s) [the ghost field], f32 spectra
// partials, inverse real FFT = radix-3 split x (256x256 four-step, ALL f32).
// Forward: k = b + 768a, S_e(b+768a) = FFT512_a{ z_e[u]*T_b[u] }; Hermitian
// trick -> b in [0,384]. FFT-512 = 3 in-place radix-8 stages, wave-private,
// register-staged.
// R16 = R14 exact (best validated: 132.5 us, absmax 2.384e-07).
// R15 LESSON: hipLaunchCooperativeKernel is POISON in this harness (+51 us —
// breaks the graph-capture fast path; fixed penalty ~55 us vs the ~4.6 us
// slot it saves). Do not use cooperative launch here.
// Launch-slot calibration (R13->R14): one regular kernel slot ~4.6 us; the
// stable ~84 us non-forward budget is mostly fixed harness overhead + a few
// us per small kernel.

__device__ __forceinline__ float2 cmulf(float2 a, float2 b) {
    return make_float2(a.x*b.x - a.y*b.y, a.x*b.y + a.y*b.x);
}
__device__ __forceinline__ float2 CADD(float2 a, float2 b){ return make_float2(a.x+b.x, a.y+b.y); }
__device__ __forceinline__ float2 CSUB(float2 a, float2 b){ return make_float2(a.x-b.x, a.y-b.y); }

// sin/cos of the EXACT value of a float32 phase (magnitude up to ~8e5):
// exact mod-2pi reduction in double via two fmas, then fast f32 sincos.
__device__ __forceinline__ void phase_sc(float th32, float* ps, float* pc) {
    const double th = (double)th32;
    const double n  = rint(th * 0.15915494309189535);
    double r = fma(-n, 6.283185307179586, th);
    r = fma(-n, 2.4492935982947064e-16, r);
    __sincosf((float)r, ps, pc);
}

// forward DFT-8 on registers (verified, R8)
#define RT2 0.70710678118654752f
#define DFT8F(A0,A1,A2,A3,A4,A5,A6,A7, X0,X1,X2,X3,X4,X5,X6,X7) { \
  float2 b0=CADD(A0,A4), b1=CADD(A1,A5), b2=CADD(A2,A6), b3=CADD(A3,A7); \
  float2 c0=CSUB(A0,A4); \
  float2 d1=CSUB(A1,A5), d2=CSUB(A2,A6), d3=CSUB(A3,A7); \
  float2 c1=make_float2((d1.x+d1.y)*RT2, (d1.y-d1.x)*RT2); \
  float2 c2=make_float2(d2.y, -d2.x); \
  float2 c3=make_float2((d3.y-d3.x)*RT2, -(d3.x+d3.y)*RT2); \
  float2 t0=CADD(b0,b2), t1=CSUB(b0,b2), t2=CADD(b1,b3), t3=CSUB(b1,b3); \
  X0=CADD(t0,t2); X4=CSUB(t0,t2); \
  X2=make_float2(t1.x+t3.y, t1.y-t3.x); X6=make_float2(t1.x-t3.y, t1.y+t3.x); \
  t0=CADD(c0,c2); t1=CSUB(c0,c2); t2=CADD(c1,c3); t3=CSUB(c1,c3); \
  X1=CADD(t0,t2); X5=CSUB(t0,t2); \
  X3=make_float2(t1.x+t3.y, t1.y-t3.x); X7=make_float2(t1.x-t3.y, t1.y+t3.x); \
}

// ---------------------------------------------------------------------------
// K1 (merged): blocks 0..384: Ttab row b (lane-transposed for K3).
// Block 385: Twf + Tk + Tm tables (read only by LATER launches).
// Blocks 386..513: event e = blk-386 — recompute own latent/offset ancestor
// chain (bit-identical op sequence), then mix->window(inline)->norm->amp,
// store lane-transposed zf and sF[e]. No intra-launch dependencies.
// ---------------------------------------------------------------------------
__global__ __launch_bounds__(256) void init_events(
    const float* __restrict__ base, const float* __restrict__ to_off_w,
    const float* __restrict__ split_w, const float* __restrict__ split_b,
    const float* __restrict__ atoms, const float* __restrict__ to_atoms_w,
    const float* __restrict__ to_atoms_b, const float* __restrict__ to_amp_w,
    const float* __restrict__ to_amp_b,
    float* __restrict__ sF, float2* __restrict__ Twf,
    float2* __restrict__ Ttab,
    float2* __restrict__ Tk, float2* __restrict__ Tm,
    float* __restrict__ zf)
{
    const int blk = blockIdx.x;
    const int tid = threadIdx.x;
    if (blk < 385) {
        const int b = blk;                       // 0..384
        for (int j = tid; j < 512; j += 256) {
            double s, c;
            sincos(-TWO_PI*(double)(b*j)/(double)NFFT, &s, &c);
            Ttab[b*512 + (j & 63)*8 + (j >> 6)] = make_float2((float)c, (float)s);
        }
        return;
    }
    if (blk == 385) {
        double s, c;
        sincos(TWO_PI*(double)tid/256.0,   &s, &c); Twf[tid]       = make_float2((float)c,(float)s);
        sincos(TWO_PI*(double)tid/512.0,   &s, &c); Twf[256 + tid] = make_float2((float)c,(float)s);
        sincos(TWO_PI*(double)tid/768.0,   &s, &c); Twf[512 + tid] = make_float2((float)c,(float)s);
        sincos(TWO_PI*(double)tid/65536.0, &s, &c); Twf[768 + tid] = make_float2((float)c,(float)s);
        // inv_a twiddle: e^{2pi i k0/NFFT}, k0 in [0,768)
        for (int k0 = tid; k0 < 768; k0 += 256) {
            sincos(TWO_PI*(double)k0/(double)NFFT, &s, &c);
            Tk[k0] = make_float2((float)c, (float)s);
        }
        // inv_b twiddle: e^{2pi i m1/MHALF}, m1 in [0,256)
        {
            sincos(TWO_PI*(double)tid/(double)MHALF, &s, &c);
            Tm[tid] = make_float2((float)c, (float)s);
        }
        return;
    }

    // ---- event block: e = blk - 386 ----
    const int e = blk - 386;
    __shared__ float xcur[LDIM], xnxt[LDIM];
    __shared__ float btS;
    __shared__ float mixS[32];
    __shared__ float evS[ASIZE];
    __shared__ double red[256];
    __shared__ float scl[2];

    // recompute latent/offset ancestor chain (bit-identical op sequence)
    if (tid < LDIM) xcur[tid] = base[tid];
    if (tid == 0) btS = 0.0f;
    __syncthreads();
    for (int i = 0; i < NLAYER; ++i) {
        const int j = (e >> (6 - i)) & 1;
        const float scale = 1.0f / (float)(1 << i);
        if (tid < LDIM) {
            const float* wr = split_w + (i*32 + j*16 + tid)*LDIM;
            float s = __fmul_rn(xcur[0], wr[0]);
            for (int l = 1; l < LDIM; ++l)
                s = __fadd_rn(s, __fmul_rn(xcur[l], wr[l]));
            s = __fadd_rn(s, split_b[i*32 + j*16 + tid]);
            xnxt[tid] = s;
        }
        if (tid == 64) {       // other wave: offset chain (reads xcur only)
            const float* wr = to_off_w + (i*2 + j)*LDIM;
            float v = __fmul_rn(xcur[0], wr[0]);
            for (int l = 1; l < LDIM; ++l)
                v = __fadd_rn(v, __fmul_rn(xcur[l], wr[l]));
            const float ef = (float)exp(-(double)v);
            const float sg = __fdiv_rn(1.0f, __fadd_rn(1.0f, ef));
            btS = __fadd_rn(btS, __fmul_rn(sg, scale));
        }
        __syncthreads();
        if (tid < LDIM) xcur[tid] = xnxt[tid];
        __syncthreads();
    }
    if (tid == 0)
        sF[e] = __fmul_rn(__fmul_rn(btS, 131072.0f), 0.5f);

    // mix -> window(inline, bit-identical) -> norm -> amp (strict f32 chain)
    if (tid < 32) {
        const float* wr = to_atoms_w + tid*LDIM;
        float m = __fmul_rn(xcur[0], wr[0]);
        for (int l = 1; l < LDIM; ++l) m = __fadd_rn(m, __fmul_rn(xcur[l], wr[l]));
        mixS[tid] = __fadd_rn(m, to_atoms_b[tid]);
    }
    __syncthreads();
    double ss = 0.0;
    for (int u = tid; u < ASIZE; u += 256) {
        float v = __fmul_rn(mixS[0], atoms[u]);
        for (int a = 1; a < 32; ++a)
            v = __fadd_rn(v, __fmul_rn(mixS[a], atoms[a*ASIZE + u]));
        const float ang = __fdiv_rn(__fmul_rn(6.283185307179586f, (float)u), 512.0f);
        const float cw = (float)cos((double)ang);
        const float w  = __fsub_rn(0.54f, __fmul_rn(0.46f, cw));
        v = __fmul_rn(v, w);
        evS[u] = v;
        ss += (double)v * (double)v;
    }
    red[tid] = ss; __syncthreads();
    for (int s = 128; s > 0; s >>= 1) { if (tid < s) red[tid] += red[tid+s]; __syncthreads(); }
    if (tid == 0) {
        const float nf = (float)sqrt(red[0]);
        scl[0] = __fadd_rn(nf, 1e-8f);
        float a = __fmul_rn(xcur[0], to_amp_w[0]);
        for (int l = 1; l < LDIM; ++l) a = __fadd_rn(a, __fmul_rn(xcur[l], to_amp_w[l]));
        scl[1] = __fadd_rn(a, to_amp_b[0]);
    }
    __syncthreads();
    const float den = scl[0], amp = scl[1];
    for (int u = tid; u < ASIZE; u += 256)
        zf[e*ASIZE + (u & 63)*8 + (u >> 6)] =
            __fmul_rn(__fdiv_rn(evS[u], den), amp);
}

// ---------------------------------------------------------------------------
// K3 (hot): forward, in-place radix-8^3 FFT-512 per wave (R10-exact, 48 us).
// T row in registers (loop-invariant), z via 2x dwordx4 + software pipeline,
// se from sF per-iteration. Launch bound (256,3): R9's (256,4) forced spills;
// R11's in-register twiddle powers regressed (compiler remat'd sincosf).
// ---------------------------------------------------------------------------
__global__ __launch_bounds__(256, 3) void forward_v3(
    const float* __restrict__ zf, const float* __restrict__ sF,
    const float2* __restrict__ Ttab, float* __restrict__ Hqf)
{
    __shared__ float2 FB[4*576];        // 18432 B wave-private padded buffers
    const int b       = blockIdx.x >> 2;     // 0..384
    const int quarter = blockIdx.x & 3;
    const int tid  = threadIdx.x;
    const int wave = tid >> 6, lane = tid & 63;
    float2* F = FB + wave*576;
    const int e0 = quarter*32;

    // T row -> 8 float2 registers (lane-transposed layout, 4x dwordx4, once)
    const float4* Tg4 = (const float4*)(Ttab + b*512 + lane*8);
    const float4 tA = Tg4[0], tB = Tg4[1], tC = Tg4[2], tD = Tg4[3];
    const float2 T0 = make_float2(tA.x, tA.y), T1 = make_float2(tA.z, tA.w);
    const float2 T2 = make_float2(tB.x, tB.y), T3 = make_float2(tB.z, tB.w);
    const float2 T4 = make_float2(tC.x, tC.y), T5 = make_float2(tC.z, tC.w);
    const float2 T6 = make_float2(tD.x, tD.y), T7 = make_float2(tD.z, tD.w);

    // register twiddle bases (FFT-internal; slop-tolerant)
    float2 w0b, w1b;
    __sincosf(-6.283185307179586f/512.0f * (float)lane,        &w0b.y, &w0b.x);
    __sincosf(-6.283185307179586f/64.0f  * (float)(lane >> 3), &w1b.y, &w1b.x);

    // f32 phase coefficient chains (bit-identical to np)
    float c2a[4], c2b[4];
    #pragma unroll
    for (int j = 0; j < 4; ++j) {
        const int a  = lane + 64*j;
        const int k1 = b + 768*a;
        const int k2 = (768 - b) + 768*(255 - a);
        c2a[j] = __fdiv_rn(__fmul_rn((float)(2*k1), 3.14159274101257324f), 196609.0f);
        c2b[j] = __fdiv_rn(__fmul_rn((float)(2*k2), 3.14159274101257324f), 196609.0f);
    }

    float a1R[4]={0,0,0,0}, a1I[4]={0,0,0,0};
    float a2R[4]={0,0,0,0}, a2I[4]={0,0,0,0};
    const int ph = lane + (lane >> 3);        // padded read base

    // z pipeline: lane-transposed layout, 2x dwordx4 per event; stride
    // between events = 512 floats = 128 float4.
    const float4* zp4 = (const float4*)(zf + (e0 + wave*8)*ASIZE + lane*8);
    float4 za = zp4[0], zb = zp4[1];

    for (int it = 0; it < 8; ++it) {
        const float sev = sF[e0 + wave*8 + it];   // wave-uniform scalar load
        // ---- stage 0 (st=1, p=lane): inputs z*T in registers
        {
            const float2 i0 = make_float2(za.x*T0.x, za.x*T0.y);
            const float2 i1 = make_float2(za.y*T1.x, za.y*T1.y);
            const float2 i2 = make_float2(za.z*T2.x, za.z*T2.y);
            const float2 i3 = make_float2(za.w*T3.x, za.w*T3.y);
            const float2 i4 = make_float2(zb.x*T4.x, zb.x*T4.y);
            const float2 i5 = make_float2(zb.y*T5.x, zb.y*T5.y);
            const float2 i6 = make_float2(zb.z*T6.x, zb.z*T6.y);
            const float2 i7 = make_float2(zb.w*T7.x, zb.w*T7.y);
            // prefetch next event's z (values consumed above). At it=7 this
            // reads 64B past zf, which is the (allocated) Ttab region — safe,
            // value unused.
            za = zp4[(it+1)*128];
            zb = zp4[(it+1)*128 + 1];
            float2 x0,x1,x2,x3,x4,x5,x6,x7;
            DFT8F(i0,i1,i2,i3,i4,i5,i6,i7, x0,x1,x2,x3,x4,x5,x6,x7);
            const int ob = 9*lane;                 // phys(8p+m) = 9p+m
            float2 wm = w0b;
            F[ob]   = x0;
            F[ob+1] = cmulf(x1, wm); wm = cmulf(wm, w0b);
            F[ob+2] = cmulf(x2, wm); wm = cmulf(wm, w0b);
            F[ob+3] = cmulf(x3, wm); wm = cmulf(wm, w0b);
            F[ob+4] = cmulf(x4, wm); wm = cmulf(wm, w0b);
            F[ob+5] = cmulf(x5, wm); wm = cmulf(wm, w0b);
            F[ob+6] = cmulf(x6, wm); wm = cmulf(wm, w0b);
            F[ob+7] = cmulf(x7, wm);
        }
        // ---- stage 1 (st=8): in-place (whole-wave reads precede writes)
        {
            const float2 i0 = F[ph      ], i1 = F[ph +  72], i2 = F[ph + 144],
                         i3 = F[ph + 216], i4 = F[ph + 288], i5 = F[ph + 360],
                         i6 = F[ph + 432], i7 = F[ph + 504];
            float2 x0,x1,x2,x3,x4,x5,x6,x7;
            DFT8F(i0,i1,i2,i3,i4,i5,i6,i7, x0,x1,x2,x3,x4,x5,x6,x7);
            const int q = lane & 7, p = lane >> 3;
            const int ob = q + 72*p;               // phys(q+64p+8m) = q+72p+9m
            float2 wm = w1b;
            F[ob]    = x0;
            F[ob+ 9] = cmulf(x1, wm); wm = cmulf(wm, w1b);
            F[ob+18] = cmulf(x2, wm); wm = cmulf(wm, w1b);
            F[ob+27] = cmulf(x3, wm); wm = cmulf(wm, w1b);
            F[ob+36] = cmulf(x4, wm); wm = cmulf(wm, w1b);
            F[ob+45] = cmulf(x5, wm); wm = cmulf(wm, w1b);
            F[ob+54] = cmulf(x6, wm); wm = cmulf(wm, w1b);
            F[ob+63] = cmulf(x7, wm);
        }
        // ---- stage 2 (st=64, p=0): outputs in registers, Y[m] = bin(lane+64m)
        float2 Y[8];
        {
            const float2 i0 = F[ph      ], i1 = F[ph +  72], i2 = F[ph + 144],
                         i3 = F[ph + 216], i4 = F[ph + 288], i5 = F[ph + 360],
                         i6 = F[ph + 432], i7 = F[ph + 504];
            DFT8F(i0,i1,i2,i3,i4,i5,i6,i7, Y[0],Y[1],Y[2],Y[3],Y[4],Y[5],Y[6],Y[7]);
        }
        // ---- accumulate
        #pragma unroll
        for (int j = 0; j < 4; ++j) {
            float ps, pc;
            const float2 S0 = Y[j];
            phase_sc(__fmul_rn(c2a[j], sev), &ps, &pc);
            a1R[j] = fmaf(S0.x, pc, fmaf(-S0.y, ps, a1R[j]));
            a1I[j] = fmaf(S0.x, ps, fmaf( S0.y, pc, a1I[j]));
            const float2 S1 = Y[j+4];   // conj(S1) * e^{i theta}
            phase_sc(__fmul_rn(c2b[j], sev), &ps, &pc);
            a2R[j] = fmaf(S1.x, pc, fmaf( S1.y, ps, a2R[j]));
            a2I[j] = fmaf(S1.x, ps, fmaf(-S1.y, pc, a2I[j]));
        }
    }

    // ---- cross-wave reduction (2 rounds in the FFT region) + stores
    float* redF = (float*)FB;
    #pragma unroll
    for (int round = 0; round < 2; ++round) {
        __syncthreads();
        const int j0 = 2*round;
        float* my = redF + (wave*64 + lane)*8;
        my[0]=a1R[j0];   my[1]=a1I[j0];   my[2]=a2R[j0];   my[3]=a2I[j0];
        my[4]=a1R[j0+1]; my[5]=a1I[j0+1]; my[6]=a2R[j0+1]; my[7]=a2I[j0+1];
        __syncthreads();
        const int s = tid >> 2, c = tid & 3;
        #pragma unroll
        for (int jr = 0; jr < 2; ++jr) {
            float v = 0.f;
            #pragma unroll
            for (int w = 0; w < 4; ++w) v += redF[(w*64 + s)*8 + jr*4 + c];
            const int as = s + 64*(j0 + jr);
            if (c < 2) {
                Hqf[2*(quarter*196609 + b*256 + as) + c] = v;
            } else if (b != 384) {
                if (b != 0)
                    Hqf[2*(quarter*196609 + (768-b)*256 + (255-as)) + (c-2)] = v;
                else if (as == 0)
                    Hqf[2*(quarter*196609 + 196608) + (c-2)] = v;
            }
        }
    }
}

// ---------------------------------------------------------------------------
// inverse radix-4 Stockham stage over 256 points, 64 threads, f32, table
// twiddles (w = e^{+2pi i p*st/256} = Tw256f[p*st]; math verified R6-R8).
// ---------------------------------------------------------------------------
__device__ __forceinline__ void ifft256f_stage(
    const float2* __restrict__ src, float2* __restrict__ dst, int t, int s4,
    const float2* __restrict__ Tw256f)
{
    const int lg = 2*s4, st = 1 << lg;
    const int q = t & (st-1), p = t >> lg;
    const float2 A0 = src[t], A1 = src[t+64], A2 = src[t+128], A3 = src[t+192];
    const float Pr = A0.x + A2.x, Pi_ = A0.y + A2.y;
    const float Qr = A0.x - A2.x, Qi  = A0.y - A2.y;
    const float Rr = A1.x + A3.x, Ri  = A1.y + A3.y;
    const float Sr = A1.x - A3.x, Si  = A1.y - A3.y;
    const int tw = p*st;
    const float2 w1 = Tw256f[tw];
    const float2 w2 = Tw256f[(2*tw) & 255];
    const float2 w3 = Tw256f[(3*tw) & 255];
    const int o = q + 4*st*p;
    dst[o] = make_float2(Pr + Rr, Pi_ + Ri);
    const float u1r = Qr - Si, u1i = Qi + Sr;
    dst[o + st]   = make_float2(u1r*w1.x - u1i*w1.y, u1r*w1.y + u1i*w1.x);
    const float u2r = Pr - Rr, u2i = Pi_ - Ri;
    dst[o + 2*st] = make_float2(u2r*w2.x - u2i*w2.y, u2r*w2.y + u2i*w2.x);
    const float u3r = Qr + Si, u3i = Qi - Sr;
    dst[o + 3*st] = make_float2(u3r*w3.x - u3i*w3.y, u3r*w3.y + u3i*w3.x);
}

// ---------------------------------------------------------------------------
// K4: inverse four-step, stage A. ONE single-wave block per job (l, j1):
// sum 4 quarter-partials of H at k = 3j1+l+768j2 (+ Hermitian partner),
// pack G inline, f32 FFT-256 over j2, four-step twiddle, TRANSPOSED store
// Yg[m1*768 + job] (coalesced reads in stage B). No barriers (1 wave).
// k0 twiddle from Tk table (bit-identical values, no per-thread fp64 sincos).
// ---------------------------------------------------------------------------
__global__ __launch_bounds__(64) void inv_a(
    const float* __restrict__ Hqf, const float2* __restrict__ Twf,
    const float2* __restrict__ Tk, float2* __restrict__ Yg)
{
    __shared__ float2 buf[512];
    const int t = threadIdx.x;
    const int job = blockIdx.x;                 // 0..767
    const int l = job >> 8, j1 = job & 255;
    const int k0 = 3*j1 + l;
    float2* A = buf; float2* B = buf + 256;
    const float2* Hq2 = (const float2*)Hqf;
    const float2* Tw256f = Twf;
    const float2* Tw512f = Twf + 256;
    const float2* Tw64kf = Twf + 768;

    const float2 tkv = Tk[k0];                  // e^{2pi i k0/NFFT}
    const float Scf = tkv.x, Ssf = tkv.y;

    #pragma unroll
    for (int r = 0; r < 4; ++r) {
        const int j2 = t + 64*r;
        const int idxK = k0*256 + j2;
        int idxM;
        if (k0 > 0) idxM = (768 - k0)*256 + (255 - j2);
        else        idxM = (j2 == 0) ? 196608 : (256 - j2);
        float hkR=0.f, hkI=0.f, hmR=0.f, hmI=0.f;
        #pragma unroll
        for (int q = 0; q < 4; ++q) {
            const float2 vk = Hq2[q*196609 + idxK];
            const float2 vm = Hq2[q*196609 + idxM];
            hkR += vk.x; hkI += vk.y;
            hmR += vm.x; hmI += vm.y;
        }
        if (k0 == 0 && j2 == 0) { hkI = 0.f; hmI = 0.f; }  // irfft Im-drop
        const float Pr = hkR + hmR, Pi_ = hkI - hmI;
        const float Qr = hkR - hmR, Qi = hkI + hmI;
        const float2 t5 = Tw512f[j2];                  // e^{2pi i j2/512}
        const float Wc = Scf*t5.x - Ssf*t5.y;          // e^{2pi i k/NFFT}
        const float Wsn = Scf*t5.y + Ssf*t5.x;
        const float WQr = Wc*Qr - Wsn*Qi;
        const float WQi = Wc*Qi + Wsn*Qr;
        A[j2] = make_float2(0.5f*(Pr - WQi), 0.5f*(Pi_ + WQr));
    }

    ifft256f_stage(A, B, t, 0, Tw256f);
    ifft256f_stage(B, A, t, 1, Tw256f);
    ifft256f_stage(A, B, t, 2, Tw256f);
    ifft256f_stage(B, A, t, 3, Tw256f);

    #pragma unroll
    for (int r = 0; r < 4; ++r) {
        const int m1 = t + 64*r;
        const float2 v = A[m1];
        const int vv = j1*m1;
        const float2 wa = Tw256f[vv >> 8];
        const float2 wb = Tw64kf[vv & 255];
        const float twc = wa.x*wb.x - wa.y*wb.y;
        const float tws = wa.x*wb.y + wa.y*wb.x;
        Yg[m1*768 + job] = make_float2(v.x*twc - v.y*tws, v.x*tws + v.y*twc);
    }
}

// ---------------------------------------------------------------------------
// K5: inverse four-step, stage B + radix-3 combine + 1/M + f32 output.
// Block per m1, 192 threads = 3 single-wave FFT jobs (l = 0..2), then combine.
// m1 twiddle from Tm table (bit-identical values).
// ---------------------------------------------------------------------------
__global__ __launch_bounds__(192) void inv_b(
    const float2* __restrict__ Yg, const float2* __restrict__ Twf,
    const float2* __restrict__ Tm, float* __restrict__ out)
{
    __shared__ float2 buf[3*512];
    const int m1 = blockIdx.x;
    const int tid = threadIdx.x;
    const int l = tid >> 6, t = tid & 63;
    const float2* Tw256f = Twf;
    const float2* Tw768f = Twf + 512;
    {
        float2* A = buf + l*512;
        float2* B = A + 256;
        #pragma unroll
        for (int r = 0; r < 4; ++r) {
            const int j1 = t + 64*r;
            A[j1] = Yg[m1*768 + l*256 + j1];      // coalesced
        }
        ifft256f_stage(A, B, t, 0, Tw256f);
        ifft256f_stage(B, A, t, 1, Tw256f);
        ifft256f_stage(A, B, t, 2, Tw256f);
        ifft256f_stage(B, A, t, 3, Tw256f);
    }
    __syncthreads();

    const float2 tmv = Tm[m1];                    // e^{2pi i m1/MHALF}
    const float cm = tmv.x, sm = tmv.y;
    const float inv = 1.0f/(float)MHALF;
    for (int m2 = tid; m2 < 256; m2 += 192) {
        const float2 F0 = buf[m2];
        const float2 F1 = buf[512 + m2];
        const float2 F2 = buf[1024 + m2];
        const float2 t7 = Tw768f[m2];                 // e^{2pi i m2/768}
        const float w1c = cm*t7.x - sm*t7.y, w1s = cm*t7.y + sm*t7.x;
        const float w2c = w1c*w1c - w1s*w1s, w2s = 2.0f*w1c*w1s;
        const float gr = F0.x + (w1c*F1.x - w1s*F1.y) + (w2c*F2.x - w2s*F2.y);
        const float gi = F0.y + (w1c*F1.y + w1s*F1.x) + (w2c*F2.y + w2s*F2.x);
        const int m = m1 + 256*m2;
        out[2*m]     = gr*inv;
        out[2*m + 1] = gi*inv;
    }
}

// ---------------------------------------------------------------------------
extern "C" void kernel_launch(void* const* d_in, const int* in_sizes, int n_in,
                              void* d_out, int out_size, void* d_ws, size_t ws_size,
                              hipStream_t stream) {
    const float* base       = (const float*)d_in[0];
    const float* to_off_w   = (const float*)d_in[1];
    const float* split_w    = (const float*)d_in[2];
    const float* split_b    = (const float*)d_in[3];
    const float* atoms      = (const float*)d_in[4];
    const float* to_atoms_w = (const float*)d_in[5];
    const float* to_atoms_b = (const float*)d_in[6];
    const float* to_amp_w   = (const float*)d_in[7];
    const float* to_amp_b   = (const float*)d_in[8];
    float* out = (float*)d_out;

    // workspace layout: 8,147,488 B (< 9,715,728 proven-safe in R4).
    // Yg aliases Ttab: forward (last Ttab reader) completes before inv_a.
    // Tk/Tm live in the old xF slot [8704, 16896).
    // NOTE: forward_v3's z-prefetch at it=7 reads 64B past zf, landing in
    // Ttab — allocated memory, value unused.
    char* ws = (char*)d_ws;
    float2* Twf  = (float2*)(ws + 0);          // 4*256*8 = 8192
    float*  sF   = (float*)(ws + 8192);        //   512
    float2* Tk   = (float2*)(ws + 8704);       // 768*8 = 6144 -> 14848
    float2* Tm   = (float2*)(ws + 14848);      // 256*8 = 2048 -> 16896
    float*  zf   = (float*)(ws + 16896);       // 262144 -> 279040
    float2* Ttab = (float2*)(ws + 279040);     // 385*512*8 = 1576960 -> 1856000
    float2* Yg   = (float2*)(ws + 279040);     // 768*256*8 = 1572864 (alias)
    float*  Hqf  = (float*)(ws + 1856000);     // 4*196609*8 = 6291488 -> 8147488

    init_events<<<514, 256, 0, stream>>>(base, to_off_w, split_w, split_b,
                                         atoms, to_atoms_w, to_atoms_b,
                                         to_amp_w, to_amp_b,
                                         sF, Twf, Ttab, Tk, Tm, zf);
    forward_v3<<<385*4, 256, 0, stream>>>(zf, sF, Ttab, Hqf);
    inv_a<<<768, 64, 0, stream>>>(Hqf, Twf, Tk, Yg);
    inv_b<<<256, 192, 0, stream>>>(Yg, Twf, Tm, out);
}

// Round 11
// 131.630 us; speedup vs baseline: 1.3944x; 1.0067x over previous
//
#include <hip/hip_runtime.h>
#include <hip/hip_bf16.h>
#include <math.h>

// Problem constants
constexpr int NSAMP  = 131072;
constexpr int NEV    = 128;
constexpr int ASIZE  = 512;
constexpr int LDIM   = 16;
constexpr int NLAYER = 7;
constexpr int NFFT   = 393216;     // padded FFT length (3*NSAMP)
constexpr int MHALF  = 196608;     // NFFT/2
constexpr double TWO_PI = 6.283185307179586;

// Pipeline: f32-faithful front-end (bit-exact bt -> s), f32-quantized phases
// theta = f32(f32(2k*pi_f32)/196609f * s) [the ghost field], f32 spectra
// partials, inverse real FFT = radix-3 split x (256x256 four-step, ALL f32).
// Forward: k = b + 768a, S_e(b+768a) = FFT512_a{ z_e[u]*T_b[u] }; Hermitian
// trick -> b in [0,384]. FFT-512 = 3 in-place radix-8 stages, wave-private,
// register-staged.
// R17 = R16 (132.5 us validated) + phase_sc f64 -> f32 Cody-Waite:
// n = rintf(th/2pi) (n <= 131072, exact in f32), r = fmaf(-n,hi,th) then
// fmaf(-n,mid,r) with hi=f32(2pi), mid=f32(2pi-hi). Angle error <= ~5e-7
// (vs ~1e-12 for the f64 path) -> output absmax expected ~0.5-1.5e-6,
// threshold 3.757e-6. Removes ~40 half-rate f64 VALU ops per lane-iteration
// from the serialized accumulate chain + frees f64 VGPR pairs.
// R15 LESSON: hipLaunchCooperativeKernel is POISON in this harness (+51 us).
// Launch-slot calibration (R13->R14): one regular kernel slot ~4.6 us.

__device__ __forceinline__ float2 cmulf(float2 a, float2 b) {
    return make_float2(a.x*b.x - a.y*b.y, a.x*b.y + a.y*b.x);
}
__device__ __forceinline__ float2 CADD(float2 a, float2 b){ return make_float2(a.x+b.x, a.y+b.y); }
__device__ __forceinline__ float2 CSUB(float2 a, float2 b){ return make_float2(a.x-b.x, a.y-b.y); }

// sin/cos of (approximately) the exact value of a float32 phase (magnitude
// up to ~8e5): f32 Cody-Waite mod-2pi reduction (2 FMA terms; n exact in
// f32 since n <= 131072 < 2^24), then fast f32 sincos. Angle error ~5e-7.
__device__ __forceinline__ void phase_sc(float th32, float* ps, float* pc) {
    const float n = rintf(__fmul_rn(th32, 0.15915494309189535f));
    float r = __builtin_fmaf(-n, 6.2831854820251465e+0f, th32);   // hi = f32(2pi)
    r = __builtin_fmaf(-n, -1.7484556000744834e-7f, r);           // mid = 2pi - hi
    __sincosf(r, ps, pc);
}

// forward DFT-8 on registers (verified, R8)
#define RT2 0.70710678118654752f
#define DFT8F(A0,A1,A2,A3,A4,A5,A6,A7, X0,X1,X2,X3,X4,X5,X6,X7) { \
  float2 b0=CADD(A0,A4), b1=CADD(A1,A5), b2=CADD(A2,A6), b3=CADD(A3,A7); \
  float2 c0=CSUB(A0,A4); \
  float2 d1=CSUB(A1,A5), d2=CSUB(A2,A6), d3=CSUB(A3,A7); \
  float2 c1=make_float2((d1.x+d1.y)*RT2, (d1.y-d1.x)*RT2); \
  float2 c2=make_float2(d2.y, -d2.x); \
  float2 c3=make_float2((d3.y-d3.x)*RT2, -(d3.x+d3.y)*RT2); \
  float2 t0=CADD(b0,b2), t1=CSUB(b0,b2), t2=CADD(b1,b3), t3=CSUB(b1,b3); \
  X0=CADD(t0,t2); X4=CSUB(t0,t2); \
  X2=make_float2(t1.x+t3.y, t1.y-t3.x); X6=make_float2(t1.x-t3.y, t1.y+t3.x); \
  t0=CADD(c0,c2); t1=CSUB(c0,c2); t2=CADD(c1,c3); t3=CSUB(c1,c3); \
  X1=CADD(t0,t2); X5=CSUB(t0,t2); \
  X3=make_float2(t1.x+t3.y, t1.y-t3.x); X7=make_float2(t1.x-t3.y, t1.y+t3.x); \
}

// ---------------------------------------------------------------------------
// K1 (merged): blocks 0..384: Ttab row b (lane-transposed for K3).
// Block 385: Twf + Tk + Tm tables (read only by LATER launches).
// Blocks 386..513: event e = blk-386 — recompute own latent/offset ancestor
// chain (bit-identical op sequence), then mix->window(inline)->norm->amp,
// store lane-transposed zf and sF[e]. No intra-launch dependencies.
// ---------------------------------------------------------------------------
__global__ __launch_bounds__(256) void init_events(
    const float* __restrict__ base, const float* __restrict__ to_off_w,
    const float* __restrict__ split_w, const float* __restrict__ split_b,
    const float* __restrict__ atoms, const float* __restrict__ to_atoms_w,
    const float* __restrict__ to_atoms_b, const float* __restrict__ to_amp_w,
    const float* __restrict__ to_amp_b,
    float* __restrict__ sF, float2* __restrict__ Twf,
    float2* __restrict__ Ttab,
    float2* __restrict__ Tk, float2* __restrict__ Tm,
    float* __restrict__ zf)
{
    const int blk = blockIdx.x;
    const int tid = threadIdx.x;
    if (blk < 385) {
        const int b = blk;                       // 0..384
        for (int j = tid; j < 512; j += 256) {
            double s, c;
            sincos(-TWO_PI*(double)(b*j)/(double)NFFT, &s, &c);
            Ttab[b*512 + (j & 63)*8 + (j >> 6)] = make_float2((float)c, (float)s);
        }
        return;
    }
    if (blk == 385) {
        double s, c;
        sincos(TWO_PI*(double)tid/256.0,   &s, &c); Twf[tid]       = make_float2((float)c,(float)s);
        sincos(TWO_PI*(double)tid/512.0,   &s, &c); Twf[256 + tid] = make_float2((float)c,(float)s);
        sincos(TWO_PI*(double)tid/768.0,   &s, &c); Twf[512 + tid] = make_float2((float)c,(float)s);
        sincos(TWO_PI*(double)tid/65536.0, &s, &c); Twf[768 + tid] = make_float2((float)c,(float)s);
        // inv_a twiddle: e^{2pi i k0/NFFT}, k0 in [0,768)
        for (int k0 = tid; k0 < 768; k0 += 256) {
            sincos(TWO_PI*(double)k0/(double)NFFT, &s, &c);
            Tk[k0] = make_float2((float)c, (float)s);
        }
        // inv_b twiddle: e^{2pi i m1/MHALF}, m1 in [0,256)
        {
            sincos(TWO_PI*(double)tid/(double)MHALF, &s, &c);
            Tm[tid] = make_float2((float)c, (float)s);
        }
        return;
    }

    // ---- event block: e = blk - 386 ----
    const int e = blk - 386;
    __shared__ float xcur[LDIM], xnxt[LDIM];
    __shared__ float btS;
    __shared__ float mixS[32];
    __shared__ float evS[ASIZE];
    __shared__ double red[256];
    __shared__ float scl[2];

    // recompute latent/offset ancestor chain (bit-identical op sequence)
    if (tid < LDIM) xcur[tid] = base[tid];
    if (tid == 0) btS = 0.0f;
    __syncthreads();
    for (int i = 0; i < NLAYER; ++i) {
        const int j = (e >> (6 - i)) & 1;
        const float scale = 1.0f / (float)(1 << i);
        if (tid < LDIM) {
            const float* wr = split_w + (i*32 + j*16 + tid)*LDIM;
            float s = __fmul_rn(xcur[0], wr[0]);
            for (int l = 1; l < LDIM; ++l)
                s = __fadd_rn(s, __fmul_rn(xcur[l], wr[l]));
            s = __fadd_rn(s, split_b[i*32 + j*16 + tid]);
            xnxt[tid] = s;
        }
        if (tid == 64) {       // other wave: offset chain (reads xcur only)
            const float* wr = to_off_w + (i*2 + j)*LDIM;
            float v = __fmul_rn(xcur[0], wr[0]);
            for (int l = 1; l < LDIM; ++l)
                v = __fadd_rn(v, __fmul_rn(xcur[l], wr[l]));
            const float ef = (float)exp(-(double)v);
            const float sg = __fdiv_rn(1.0f, __fadd_rn(1.0f, ef));
            btS = __fadd_rn(btS, __fmul_rn(sg, scale));
        }
        __syncthreads();
        if (tid < LDIM) xcur[tid] = xnxt[tid];
        __syncthreads();
    }
    if (tid == 0)
        sF[e] = __fmul_rn(__fmul_rn(btS, 131072.0f), 0.5f);

    // mix -> window(inline, bit-identical) -> norm -> amp (strict f32 chain)
    if (tid < 32) {
        const float* wr = to_atoms_w + tid*LDIM;
        float m = __fmul_rn(xcur[0], wr[0]);
        for (int l = 1; l < LDIM; ++l) m = __fadd_rn(m, __fmul_rn(xcur[l], wr[l]));
        mixS[tid] = __fadd_rn(m, to_atoms_b[tid]);
    }
    __syncthreads();
    double ss = 0.0;
    for (int u = tid; u < ASIZE; u += 256) {
        float v = __fmul_rn(mixS[0], atoms[u]);
        for (int a = 1; a < 32; ++a)
            v = __fadd_rn(v, __fmul_rn(mixS[a], atoms[a*ASIZE + u]));
        const float ang = __fdiv_rn(__fmul_rn(6.283185307179586f, (float)u), 512.0f);
        const float cw = (float)cos((double)ang);
        const float w  = __fsub_rn(0.54f, __fmul_rn(0.46f, cw));
        v = __fmul_rn(v, w);
        evS[u] = v;
        ss += (double)v * (double)v;
    }
    red[tid] = ss; __syncthreads();
    for (int s = 128; s > 0; s >>= 1) { if (tid < s) red[tid] += red[tid+s]; __syncthreads(); }
    if (tid == 0) {
        const float nf = (float)sqrt(red[0]);
        scl[0] = __fadd_rn(nf, 1e-8f);
        float a = __fmul_rn(xcur[0], to_amp_w[0]);
        for (int l = 1; l < LDIM; ++l) a = __fadd_rn(a, __fmul_rn(xcur[l], to_amp_w[l]));
        scl[1] = __fadd_rn(a, to_amp_b[0]);
    }
    __syncthreads();
    const float den = scl[0], amp = scl[1];
    for (int u = tid; u < ASIZE; u += 256)
        zf[e*ASIZE + (u & 63)*8 + (u >> 6)] =
            __fmul_rn(__fdiv_rn(evS[u], den), amp);
}

// ---------------------------------------------------------------------------
// K3 (hot): forward, in-place radix-8^3 FFT-512 per wave (R10 structure).
// T row in registers (loop-invariant), z via 2x dwordx4 + software pipeline,
// se from sF per-iteration. Launch bound (256,3): R9's (256,4) forced spills;
// R11's in-register twiddle powers regressed (compiler remat'd sincosf).
// R17: phase_sc is now f32 Cody-Waite (see above).
// ---------------------------------------------------------------------------
__global__ __launch_bounds__(256, 3) void forward_v3(
    const float* __restrict__ zf, const float* __restrict__ sF,
    const float2* __restrict__ Ttab, float* __restrict__ Hqf)
{
    __shared__ float2 FB[4*576];        // 18432 B wave-private padded buffers
    const int b       = blockIdx.x >> 2;     // 0..384
    const int quarter = blockIdx.x & 3;
    const int tid  = threadIdx.x;
    const int wave = tid >> 6, lane = tid & 63;
    float2* F = FB + wave*576;
    const int e0 = quarter*32;

    // T row -> 8 float2 registers (lane-transposed layout, 4x dwordx4, once)
    const float4* Tg4 = (const float4*)(Ttab + b*512 + lane*8);
    const float4 tA = Tg4[0], tB = Tg4[1], tC = Tg4[2], tD = Tg4[3];
    const float2 T0 = make_float2(tA.x, tA.y), T1 = make_float2(tA.z, tA.w);
    const float2 T2 = make_float2(tB.x, tB.y), T3 = make_float2(tB.z, tB.w);
    const float2 T4 = make_float2(tC.x, tC.y), T5 = make_float2(tC.z, tC.w);
    const float2 T6 = make_float2(tD.x, tD.y), T7 = make_float2(tD.z, tD.w);

    // register twiddle bases (FFT-internal; slop-tolerant)
    float2 w0b, w1b;
    __sincosf(-6.283185307179586f/512.0f * (float)lane,        &w0b.y, &w0b.x);
    __sincosf(-6.283185307179586f/64.0f  * (float)(lane >> 3), &w1b.y, &w1b.x);

    // f32 phase coefficient chains (bit-identical to np)
    float c2a[4], c2b[4];
    #pragma unroll
    for (int j = 0; j < 4; ++j) {
        const int a  = lane + 64*j;
        const int k1 = b + 768*a;
        const int k2 = (768 - b) + 768*(255 - a);
        c2a[j] = __fdiv_rn(__fmul_rn((float)(2*k1), 3.14159274101257324f), 196609.0f);
        c2b[j] = __fdiv_rn(__fmul_rn((float)(2*k2), 3.14159274101257324f), 196609.0f);
    }

    float a1R[4]={0,0,0,0}, a1I[4]={0,0,0,0};
    float a2R[4]={0,0,0,0}, a2I[4]={0,0,0,0};
    const int ph = lane + (lane >> 3);        // padded read base

    // z pipeline: lane-transposed layout, 2x dwordx4 per event; stride
    // between events = 512 floats = 128 float4.
    const float4* zp4 = (const float4*)(zf + (e0 + wave*8)*ASIZE + lane*8);
    float4 za = zp4[0], zb = zp4[1];

    for (int it = 0; it < 8; ++it) {
        const float sev = sF[e0 + wave*8 + it];   // wave-uniform scalar load
        // ---- stage 0 (st=1, p=lane): inputs z*T in registers
        {
            const float2 i0 = make_float2(za.x*T0.x, za.x*T0.y);
            const float2 i1 = make_float2(za.y*T1.x, za.y*T1.y);
            const float2 i2 = make_float2(za.z*T2.x, za.z*T2.y);
            const float2 i3 = make_float2(za.w*T3.x, za.w*T3.y);
            const float2 i4 = make_float2(zb.x*T4.x, zb.x*T4.y);
            const float2 i5 = make_float2(zb.y*T5.x, zb.y*T5.y);
            const float2 i6 = make_float2(zb.z*T6.x, zb.z*T6.y);
            const float2 i7 = make_float2(zb.w*T7.x, zb.w*T7.y);
            // prefetch next event's z (values consumed above). At it=7 this
            // reads 64B past zf, which is the (allocated) Ttab region — safe,
            // value unused.
            za = zp4[(it+1)*128];
            zb = zp4[(it+1)*128 + 1];
            float2 x0,x1,x2,x3,x4,x5,x6,x7;
            DFT8F(i0,i1,i2,i3,i4,i5,i6,i7, x0,x1,x2,x3,x4,x5,x6,x7);
            const int ob = 9*lane;                 // phys(8p+m) = 9p+m
            float2 wm = w0b;
            F[ob]   = x0;
            F[ob+1] = cmulf(x1, wm); wm = cmulf(wm, w0b);
            F[ob+2] = cmulf(x2, wm); wm = cmulf(wm, w0b);
            F[ob+3] = cmulf(x3, wm); wm = cmulf(wm, w0b);
            F[ob+4] = cmulf(x4, wm); wm = cmulf(wm, w0b);
            F[ob+5] = cmulf(x5, wm); wm = cmulf(wm, w0b);
            F[ob+6] = cmulf(x6, wm); wm = cmulf(wm, w0b);
            F[ob+7] = cmulf(x7, wm);
        }
        // ---- stage 1 (st=8): in-place (whole-wave reads precede writes)
        {
            const float2 i0 = F[ph      ], i1 = F[ph +  72], i2 = F[ph + 144],
                         i3 = F[ph + 216], i4 = F[ph + 288], i5 = F[ph + 360],
                         i6 = F[ph + 432], i7 = F[ph + 504];
            float2 x0,x1,x2,x3,x4,x5,x6,x7;
            DFT8F(i0,i1,i2,i3,i4,i5,i6,i7, x0,x1,x2,x3,x4,x5,x6,x7);
            const int q = lane & 7, p = lane >> 3;
            const int ob = q + 72*p;               // phys(q+64p+8m) = q+72p+9m
            float2 wm = w1b;
            F[ob]    = x0;
            F[ob+ 9] = cmulf(x1, wm); wm = cmulf(wm, w1b);
            F[ob+18] = cmulf(x2, wm); wm = cmulf(wm, w1b);
            F[ob+27] = cmulf(x3, wm); wm = cmulf(wm, w1b);
            F[ob+36] = cmulf(x4, wm); wm = cmulf(wm, w1b);
            F[ob+45] = cmulf(x5, wm); wm = cmulf(wm, w1b);
            F[ob+54] = cmulf(x6, wm); wm = cmulf(wm, w1b);
            F[ob+63] = cmulf(x7, wm);
        }
        // ---- stage 2 (st=64, p=0): outputs in registers, Y[m] = bin(lane+64m)
        float2 Y[8];
        {
            const float2 i0 = F[ph      ], i1 = F[ph +  72], i2 = F[ph + 144],
                         i3 = F[ph + 216], i4 = F[ph + 288], i5 = F[ph + 360],
                         i6 = F[ph + 432], i7 = F[ph + 504];
            DFT8F(i0,i1,i2,i3,i4,i5,i6,i7, Y[0],Y[1],Y[2],Y[3],Y[4],Y[5],Y[6],Y[7]);
        }
        // ---- accumulate
        #pragma unroll
        for (int j = 0; j < 4; ++j) {
            float ps, pc;
            const float2 S0 = Y[j];
            phase_sc(__fmul_rn(c2a[j], sev), &ps, &pc);
            a1R[j] = fmaf(S0.x, pc, fmaf(-S0.y, ps, a1R[j]));
            a1I[j] = fmaf(S0.x, ps, fmaf( S0.y, pc, a1I[j]));
            const float2 S1 = Y[j+4];   // conj(S1) * e^{i theta}
            phase_sc(__fmul_rn(c2b[j], sev), &ps, &pc);
            a2R[j] = fmaf(S1.x, pc, fmaf( S1.y, ps, a2R[j]));
            a2I[j] = fmaf(S1.x, ps, fmaf(-S1.y, pc, a2I[j]));
        }
    }

    // ---- cross-wave reduction (2 rounds in the FFT region) + stores
    float* redF = (float*)FB;
    #pragma unroll
    for (int round = 0; round < 2; ++round) {
        __syncthreads();
        const int j0 = 2*round;
        float* my = redF + (wave*64 + lane)*8;
        my[0]=a1R[j0];   my[1]=a1I[j0];   my[2]=a2R[j0];   my[3]=a2I[j0];
        my[4]=a1R[j0+1]; my[5]=a1I[j0+1]; my[6]=a2R[j0+1]; my[7]=a2I[j0+1];
        __syncthreads();
        const int s = tid >> 2, c = tid & 3;
        #pragma unroll
        for (int jr = 0; jr < 2; ++jr) {
            float v = 0.f;
            #pragma unroll
            for (int w = 0; w < 4; ++w) v += redF[(w*64 + s)*8 + jr*4 + c];
            const int as = s + 64*(j0 + jr);
            if (c < 2) {
                Hqf[2*(quarter*196609 + b*256 + as) + c] = v;
            } else if (b != 384) {
                if (b != 0)
                    Hqf[2*(quarter*196609 + (768-b)*256 + (255-as)) + (c-2)] = v;
                else if (as == 0)
                    Hqf[2*(quarter*196609 + 196608) + (c-2)] = v;
            }
        }
    }
}

// ---------------------------------------------------------------------------
// inverse radix-4 Stockham stage over 256 points, 64 threads, f32, table
// twiddles (w = e^{+2pi i p*st/256} = Tw256f[p*st]; math verified R6-R8).
// ---------------------------------------------------------------------------
__device__ __forceinline__ void ifft256f_stage(
    const float2* __restrict__ src, float2* __restrict__ dst, int t, int s4,
    const float2* __restrict__ Tw256f)
{
    const int lg = 2*s4, st = 1 << lg;
    const int q = t & (st-1), p = t >> lg;
    const float2 A0 = src[t], A1 = src[t+64], A2 = src[t+128], A3 = src[t+192];
    const float Pr = A0.x + A2.x, Pi_ = A0.y + A2.y;
    const float Qr = A0.x - A2.x, Qi  = A0.y - A2.y;
    const float Rr = A1.x + A3.x, Ri  = A1.y + A3.y;
    const float Sr = A1.x - A3.x, Si  = A1.y - A3.y;
    const int tw = p*st;
    const float2 w1 = Tw256f[tw];
    const float2 w2 = Tw256f[(2*tw) & 255];
    const float2 w3 = Tw256f[(3*tw) & 255];
    const int o = q + 4*st*p;
    dst[o] = make_float2(Pr + Rr, Pi_ + Ri);
    const float u1r = Qr - Si, u1i = Qi + Sr;
    dst[o + st]   = make_float2(u1r*w1.x - u1i*w1.y, u1r*w1.y + u1i*w1.x);
    const float u2r = Pr - Rr, u2i = Pi_ - Ri;
    dst[o + 2*st] = make_float2(u2r*w2.x - u2i*w2.y, u2r*w2.y + u2i*w2.x);
    const float u3r = Qr + Si, u3i = Qi - Sr;
    dst[o + 3*st] = make_float2(u3r*w3.x - u3i*w3.y, u3r*w3.y + u3i*w3.x);
}

// ---------------------------------------------------------------------------
// K4: inverse four-step, stage A. ONE single-wave block per job (l, j1):
// sum 4 quarter-partials of H at k = 3j1+l+768j2 (+ Hermitian partner),
// pack G inline, f32 FFT-256 over j2, four-step twiddle, TRANSPOSED store
// Yg[m1*768 + job] (coalesced reads in stage B). No barriers (1 wave).
// k0 twiddle from Tk table (bit-identical values, no per-thread fp64 sincos).
// ---------------------------------------------------------------------------
__global__ __launch_bounds__(64) void inv_a(
    const float* __restrict__ Hqf, const float2* __restrict__ Twf,
    const float2* __restrict__ Tk, float2* __restrict__ Yg)
{
    __shared__ float2 buf[512];
    const int t = threadIdx.x;
    const int job = blockIdx.x;                 // 0..767
    const int l = job >> 8, j1 = job & 255;
    const int k0 = 3*j1 + l;
    float2* A = buf; float2* B = buf + 256;
    const float2* Hq2 = (const float2*)Hqf;
    const float2* Tw256f = Twf;
    const float2* Tw512f = Twf + 256;
    const float2* Tw64kf = Twf + 768;

    const float2 tkv = Tk[k0];                  // e^{2pi i k0/NFFT}
    const float Scf = tkv.x, Ssf = tkv.y;

    #pragma unroll
    for (int r = 0; r < 4; ++r) {
        const int j2 = t + 64*r;
        const int idxK = k0*256 + j2;
        int idxM;
        if (k0 > 0) idxM = (768 - k0)*256 + (255 - j2);
        else        idxM = (j2 == 0) ? 196608 : (256 - j2);
        float hkR=0.f, hkI=0.f, hmR=0.f, hmI=0.f;
        #pragma unroll
        for (int q = 0; q < 4; ++q) {
            const float2 vk = Hq2[q*196609 + idxK];
            const float2 vm = Hq2[q*196609 + idxM];
            hkR += vk.x; hkI += vk.y;
            hmR += vm.x; hmI += vm.y;
        }
        if (k0 == 0 && j2 == 0) { hkI = 0.f; hmI = 0.f; }  // irfft Im-drop
        const float Pr = hkR + hmR, Pi_ = hkI - hmI;
        const float Qr = hkR - hmR, Qi = hkI + hmI;
        const float2 t5 = Tw512f[j2];                  // e^{2pi i j2/512}
        const float Wc = Scf*t5.x - Ssf*t5.y;          // e^{2pi i k/NFFT}
        const float Wsn = Scf*t5.y + Ssf*t5.x;
        const float WQr = Wc*Qr - Wsn*Qi;
        const float WQi = Wc*Qi + Wsn*Qr;
        A[j2] = make_float2(0.5f*(Pr - WQi), 0.5f*(Pi_ + WQr));
    }

    ifft256f_stage(A, B, t, 0, Tw256f);
    ifft256f_stage(B, A, t, 1, Tw256f);
    ifft256f_stage(A, B, t, 2, Tw256f);
    ifft256f_stage(B, A, t, 3, Tw256f);

    #pragma unroll
    for (int r = 0; r < 4; ++r) {
        const int m1 = t + 64*r;
        const float2 v = A[m1];
        const int vv = j1*m1;
        const float2 wa = Tw256f[vv >> 8];
        const float2 wb = Tw64kf[vv & 255];
        const float twc = wa.x*wb.x - wa.y*wb.y;
        const float tws = wa.x*wb.y + wa.y*wb.x;
        Yg[m1*768 + job] = make_float2(v.x*twc - v.y*tws, v.x*tws + v.y*twc);
    }
}

// ---------------------------------------------------------------------------
// K5: inverse four-step, stage B + radix-3 combine + 1/M + f32 output.
// Block per m1, 192 threads = 3 single-wave FFT jobs (l = 0..2), then combine.
// m1 twiddle from Tm table (bit-identical values).
// ---------------------------------------------------------------------------
__global__ __launch_bounds__(192) void inv_b(
    const float2* __restrict__ Yg, const float2* __restrict__ Twf,
    const float2* __restrict__ Tm, float* __restrict__ out)
{
    __shared__ float2 buf[3*512];
    const int m1 = blockIdx.x;
    const int tid = threadIdx.x;
    const int l = tid >> 6, t = tid & 63;
    const float2* Tw256f = Twf;
    const float2* Tw768f = Twf + 512;
    {
        float2* A = buf + l*512;
        float2* B = A + 256;
        #pragma unroll
        for (int r = 0; r < 4; ++r) {
            const int j1 = t + 64*r;
            A[j1] = Yg[m1*768 + l*256 + j1];      // coalesced
        }
        ifft256f_stage(A, B, t, 0, Tw256f);
        ifft256f_stage(B, A, t, 1, Tw256f);
        ifft256f_stage(A, B, t, 2, Tw256f);
        ifft256f_stage(B, A, t, 3, Tw256f);
    }
    __syncthreads();

    const float2 tmv = Tm[m1];                    // e^{2pi i m1/MHALF}
    const float cm = tmv.x, sm = tmv.y;
    const float inv = 1.0f/(float)MHALF;
    for (int m2 = tid; m2 < 256; m2 += 192) {
        const float2 F0 = buf[m2];
        const float2 F1 = buf[512 + m2];
        const float2 F2 = buf[1024 + m2];
        const float2 t7 = Tw768f[m2];                 // e^{2pi i m2/768}
        const float w1c = cm*t7.x - sm*t7.y, w1s = cm*t7.y + sm*t7.x;
        const float w2c = w1c*w1c - w1s*w1s, w2s = 2.0f*w1c*w1s;
        const float gr = F0.x + (w1c*F1.x - w1s*F1.y) + (w2c*F2.x - w2s*F2.y);
        const float gi = F0.y + (w1c*F1.y + w1s*F1.x) + (w2c*F2.y + w2s*F2.x);
        const int m = m1 + 256*m2;
        out[2*m]     = gr*inv;
        out[2*m + 1] = gi*inv;
    }
}

// ---------------------------------------------------------------------------
extern "C" void kernel_launch(void* const* d_in, const int* in_sizes, int n_in,
                              void* d_out, int out_size, void* d_ws, size_t ws_size,
                              hipStream_t stream) {
    const float* base       = (const float*)d_in[0];
    const float* to_off_w   = (const float*)d_in[1];
    const float* split_w    = (const float*)d_in[2];
    const float* split_b    = (const float*)d_in[3];
    const float* atoms      = (const float*)d_in[4];
    const float* to_atoms_w = (const float*)d_in[5];
    const float* to_atoms_b = (const float*)d_in[6];
    const float* to_amp_w   = (const float*)d_in[7];
    const float* to_amp_b   = (const float*)d_in[8];
    float* out = (float*)d_out;

    // workspace layout: 8,147,488 B (< 9,715,728 proven-safe in R4).
    // Yg aliases Ttab: forward (last Ttab reader) completes before inv_a.
    // Tk/Tm live in the old xF slot [8704, 16896).
    // NOTE: forward_v3's z-prefetch at it=7 reads 64B past zf, landing in
    // Ttab — allocated memory, value unused.
    char* ws = (char*)d_ws;
    float2* Twf  = (float2*)(ws + 0);          // 4*256*8 = 8192
    float*  sF   = (float*)(ws + 8192);        //   512
    float2* Tk   = (float2*)(ws + 8704);       // 768*8 = 6144 -> 14848
    float2* Tm   = (float2*)(ws + 14848);      // 256*8 = 2048 -> 16896
    float*  zf   = (float*)(ws + 16896);       // 262144 -> 279040
    float2* Ttab = (float2*)(ws + 279040);     // 385*512*8 = 1576960 -> 1856000
    float2* Yg   = (float2*)(ws + 279040);     // 768*256*8 = 1572864 (alias)
    float*  Hqf  = (float*)(ws + 1856000);     // 4*196609*8 = 6291488 -> 8147488

    init_events<<<514, 256, 0, stream>>>(base, to_off_w, split_w, split_b,
                                         atoms, to_atoms_w, to_atoms_b,
                                         to_amp_w, to_amp_b,
                                         sF, Twf, Ttab, Tk, Tm, zf);
    forward_v3<<<385*4, 256, 0, stream>>>(zf, sF, Ttab, Hqf);
    inv_a<<<768, 64, 0, stream>>>(Hqf, Twf, Tk, Yg);
    inv_b<<<256, 192, 0, stream>>>(Yg, Twf, Tm, out);
}

// Round 12
// 130.597 us; speedup vs baseline: 1.4054x; 1.0079x over previous
//
#include <hip/hip_runtime.h>
#include <hip/hip_bf16.h>
#include <math.h>

// Problem constants
constexpr int NSAMP  = 131072;
constexpr int NEV    = 128;
constexpr int ASIZE  = 512;
constexpr int LDIM   = 16;
constexpr int NLAYER = 7;
constexpr int NFFT   = 393216;     // padded FFT length (3*NSAMP)
constexpr int MHALF  = 196608;     // NFFT/2
constexpr double TWO_PI = 6.283185307179586;

// Pipeline: f32-faithful front-end (bit-exact bt -> s), f32-quantized phases
// theta = f32(f32(2k*pi_f32)/196609f * s) [the ghost field], f32 spectra
// partials, inverse real FFT = radix-3 split x (256x256 four-step, ALL f32).
// Forward: k = b + 768a, S_e(b+768a) = FFT512_a{ z_e[u]*T_b[u] }; Hermitian
// trick -> b in [0,384]. FFT-512 = 3 in-place radix-8 stages, wave-private,
// register-staged.
// R18 = R17 (131.6 us validated) + twiddle-power TREE in forward stages 0/1:
// chain wm*=w (depth 6, serial into LDS writes) -> tree w2/w3/w4 + products
// (depth <=3, ~same op count, NO hoisted loop state — avoids R11's remat
// failure). Twiddle values shift within FFT slop (absmax headroom 7.9x).
// R15 LESSON: hipLaunchCooperativeKernel is POISON here (+51 us).
// Launch-slot calibration (R13->R14): one regular kernel slot ~4.6 us;
// 4 launches is the structural minimum (all boundaries are all-to-all).

__device__ __forceinline__ float2 cmulf(float2 a, float2 b) {
    return make_float2(a.x*b.x - a.y*b.y, a.x*b.y + a.y*b.x);
}
__device__ __forceinline__ float2 CADD(float2 a, float2 b){ return make_float2(a.x+b.x, a.y+b.y); }
__device__ __forceinline__ float2 CSUB(float2 a, float2 b){ return make_float2(a.x-b.x, a.y-b.y); }

// sin/cos of (approximately) the exact value of a float32 phase (magnitude
// up to ~8e5): f32 Cody-Waite mod-2pi reduction (2 FMA terms; n exact in
// f32 since n <= 131072 < 2^24), then fast f32 sincos. Angle error ~5e-7.
__device__ __forceinline__ void phase_sc(float th32, float* ps, float* pc) {
    const float n = rintf(__fmul_rn(th32, 0.15915494309189535f));
    float r = __builtin_fmaf(-n, 6.2831854820251465e+0f, th32);   // hi = f32(2pi)
    r = __builtin_fmaf(-n, -1.7484556000744834e-7f, r);           // mid = 2pi - hi
    __sincosf(r, ps, pc);
}

// forward DFT-8 on registers (verified, R8)
#define RT2 0.70710678118654752f
#define DFT8F(A0,A1,A2,A3,A4,A5,A6,A7, X0,X1,X2,X3,X4,X5,X6,X7) { \
  float2 b0=CADD(A0,A4), b1=CADD(A1,A5), b2=CADD(A2,A6), b3=CADD(A3,A7); \
  float2 c0=CSUB(A0,A4); \
  float2 d1=CSUB(A1,A5), d2=CSUB(A2,A6), d3=CSUB(A3,A7); \
  float2 c1=make_float2((d1.x+d1.y)*RT2, (d1.y-d1.x)*RT2); \
  float2 c2=make_float2(d2.y, -d2.x); \
  float2 c3=make_float2((d3.y-d3.x)*RT2, -(d3.x+d3.y)*RT2); \
  float2 t0=CADD(b0,b2), t1=CSUB(b0,b2), t2=CADD(b1,b3), t3=CSUB(b1,b3); \
  X0=CADD(t0,t2); X4=CSUB(t0,t2); \
  X2=make_float2(t1.x+t3.y, t1.y-t3.x); X6=make_float2(t1.x-t3.y, t1.y+t3.x); \
  t0=CADD(c0,c2); t1=CSUB(c0,c2); t2=CADD(c1,c3); t3=CSUB(c1,c3); \
  X1=CADD(t0,t2); X5=CSUB(t0,t2); \
  X3=make_float2(t1.x+t3.y, t1.y-t3.x); X7=make_float2(t1.x-t3.y, t1.y+t3.x); \
}

// ---------------------------------------------------------------------------
// K1 (merged): blocks 0..384: Ttab row b (lane-transposed for K3).
// Block 385: Twf + Tk + Tm tables (read only by LATER launches).
// Blocks 386..513: event e = blk-386 — recompute own latent/offset ancestor
// chain (bit-identical op sequence), then mix->window(inline)->norm->amp,
// store lane-transposed zf and sF[e]. No intra-launch dependencies.
// ---------------------------------------------------------------------------
__global__ __launch_bounds__(256) void init_events(
    const float* __restrict__ base, const float* __restrict__ to_off_w,
    const float* __restrict__ split_w, const float* __restrict__ split_b,
    const float* __restrict__ atoms, const float* __restrict__ to_atoms_w,
    const float* __restrict__ to_atoms_b, const float* __restrict__ to_amp_w,
    const float* __restrict__ to_amp_b,
    float* __restrict__ sF, float2* __restrict__ Twf,
    float2* __restrict__ Ttab,
    float2* __restrict__ Tk, float2* __restrict__ Tm,
    float* __restrict__ zf)
{
    const int blk = blockIdx.x;
    const int tid = threadIdx.x;
    if (blk < 385) {
        const int b = blk;                       // 0..384
        for (int j = tid; j < 512; j += 256) {
            double s, c;
            sincos(-TWO_PI*(double)(b*j)/(double)NFFT, &s, &c);
            Ttab[b*512 + (j & 63)*8 + (j >> 6)] = make_float2((float)c, (float)s);
        }
        return;
    }
    if (blk == 385) {
        double s, c;
        sincos(TWO_PI*(double)tid/256.0,   &s, &c); Twf[tid]       = make_float2((float)c,(float)s);
        sincos(TWO_PI*(double)tid/512.0,   &s, &c); Twf[256 + tid] = make_float2((float)c,(float)s);
        sincos(TWO_PI*(double)tid/768.0,   &s, &c); Twf[512 + tid] = make_float2((float)c,(float)s);
        sincos(TWO_PI*(double)tid/65536.0, &s, &c); Twf[768 + tid] = make_float2((float)c,(float)s);
        // inv_a twiddle: e^{2pi i k0/NFFT}, k0 in [0,768)
        for (int k0 = tid; k0 < 768; k0 += 256) {
            sincos(TWO_PI*(double)k0/(double)NFFT, &s, &c);
            Tk[k0] = make_float2((float)c, (float)s);
        }
        // inv_b twiddle: e^{2pi i m1/MHALF}, m1 in [0,256)
        {
            sincos(TWO_PI*(double)tid/(double)MHALF, &s, &c);
            Tm[tid] = make_float2((float)c, (float)s);
        }
        return;
    }

    // ---- event block: e = blk - 386 ----
    const int e = blk - 386;
    __shared__ float xcur[LDIM], xnxt[LDIM];
    __shared__ float btS;
    __shared__ float mixS[32];
    __shared__ float evS[ASIZE];
    __shared__ double red[256];
    __shared__ float scl[2];

    // recompute latent/offset ancestor chain (bit-identical op sequence)
    if (tid < LDIM) xcur[tid] = base[tid];
    if (tid == 0) btS = 0.0f;
    __syncthreads();
    for (int i = 0; i < NLAYER; ++i) {
        const int j = (e >> (6 - i)) & 1;
        const float scale = 1.0f / (float)(1 << i);
        if (tid < LDIM) {
            const float* wr = split_w + (i*32 + j*16 + tid)*LDIM;
            float s = __fmul_rn(xcur[0], wr[0]);
            for (int l = 1; l < LDIM; ++l)
                s = __fadd_rn(s, __fmul_rn(xcur[l], wr[l]));
            s = __fadd_rn(s, split_b[i*32 + j*16 + tid]);
            xnxt[tid] = s;
        }
        if (tid == 64) {       // other wave: offset chain (reads xcur only)
            const float* wr = to_off_w + (i*2 + j)*LDIM;
            float v = __fmul_rn(xcur[0], wr[0]);
            for (int l = 1; l < LDIM; ++l)
                v = __fadd_rn(v, __fmul_rn(xcur[l], wr[l]));
            const float ef = (float)exp(-(double)v);
            const float sg = __fdiv_rn(1.0f, __fadd_rn(1.0f, ef));
            btS = __fadd_rn(btS, __fmul_rn(sg, scale));
        }
        __syncthreads();
        if (tid < LDIM) xcur[tid] = xnxt[tid];
        __syncthreads();
    }
    if (tid == 0)
        sF[e] = __fmul_rn(__fmul_rn(btS, 131072.0f), 0.5f);

    // mix -> window(inline, bit-identical) -> norm -> amp (strict f32 chain)
    if (tid < 32) {
        const float* wr = to_atoms_w + tid*LDIM;
        float m = __fmul_rn(xcur[0], wr[0]);
        for (int l = 1; l < LDIM; ++l) m = __fadd_rn(m, __fmul_rn(xcur[l], wr[l]));
        mixS[tid] = __fadd_rn(m, to_atoms_b[tid]);
    }
    __syncthreads();
    double ss = 0.0;
    for (int u = tid; u < ASIZE; u += 256) {
        float v = __fmul_rn(mixS[0], atoms[u]);
        for (int a = 1; a < 32; ++a)
            v = __fadd_rn(v, __fmul_rn(mixS[a], atoms[a*ASIZE + u]));
        const float ang = __fdiv_rn(__fmul_rn(6.283185307179586f, (float)u), 512.0f);
        const float cw = (float)cos((double)ang);
        const float w  = __fsub_rn(0.54f, __fmul_rn(0.46f, cw));
        v = __fmul_rn(v, w);
        evS[u] = v;
        ss += (double)v * (double)v;
    }
    red[tid] = ss; __syncthreads();
    for (int s = 128; s > 0; s >>= 1) { if (tid < s) red[tid] += red[tid+s]; __syncthreads(); }
    if (tid == 0) {
        const float nf = (float)sqrt(red[0]);
        scl[0] = __fadd_rn(nf, 1e-8f);
        float a = __fmul_rn(xcur[0], to_amp_w[0]);
        for (int l = 1; l < LDIM; ++l) a = __fadd_rn(a, __fmul_rn(xcur[l], to_amp_w[l]));
        scl[1] = __fadd_rn(a, to_amp_b[0]);
    }
    __syncthreads();
    const float den = scl[0], amp = scl[1];
    for (int u = tid; u < ASIZE; u += 256)
        zf[e*ASIZE + (u & 63)*8 + (u >> 6)] =
            __fmul_rn(__fdiv_rn(evS[u], den), amp);
}

// ---------------------------------------------------------------------------
// K3 (hot): forward, in-place radix-8^3 FFT-512 per wave (R10 structure).
// T row in registers (loop-invariant), z via 2x dwordx4 + software pipeline,
// se from sF per-iteration. Launch bound (256,3): R9's (256,4) forced spills;
// R11's full twiddle hoist regressed (compiler remat'd sincosf).
// R17: phase_sc f32 Cody-Waite. R18: twiddle powers via depth-3 tree
// (in-loop, no hoisted state) instead of the serial depth-6 chain.
// ---------------------------------------------------------------------------
__global__ __launch_bounds__(256, 3) void forward_v3(
    const float* __restrict__ zf, const float* __restrict__ sF,
    const float2* __restrict__ Ttab, float* __restrict__ Hqf)
{
    __shared__ float2 FB[4*576];        // 18432 B wave-private padded buffers
    const int b       = blockIdx.x >> 2;     // 0..384
    const int quarter = blockIdx.x & 3;
    const int tid  = threadIdx.x;
    const int wave = tid >> 6, lane = tid & 63;
    float2* F = FB + wave*576;
    const int e0 = quarter*32;

    // T row -> 8 float2 registers (lane-transposed layout, 4x dwordx4, once)
    const float4* Tg4 = (const float4*)(Ttab + b*512 + lane*8);
    const float4 tA = Tg4[0], tB = Tg4[1], tC = Tg4[2], tD = Tg4[3];
    const float2 T0 = make_float2(tA.x, tA.y), T1 = make_float2(tA.z, tA.w);
    const float2 T2 = make_float2(tB.x, tB.y), T3 = make_float2(tB.z, tB.w);
    const float2 T4 = make_float2(tC.x, tC.y), T5 = make_float2(tC.z, tC.w);
    const float2 T6 = make_float2(tD.x, tD.y), T7 = make_float2(tD.z, tD.w);

    // register twiddle bases (FFT-internal; slop-tolerant)
    float2 w0b, w1b;
    __sincosf(-6.283185307179586f/512.0f * (float)lane,        &w0b.y, &w0b.x);
    __sincosf(-6.283185307179586f/64.0f  * (float)(lane >> 3), &w1b.y, &w1b.x);

    // f32 phase coefficient chains (bit-identical to np)
    float c2a[4], c2b[4];
    #pragma unroll
    for (int j = 0; j < 4; ++j) {
        const int a  = lane + 64*j;
        const int k1 = b + 768*a;
        const int k2 = (768 - b) + 768*(255 - a);
        c2a[j] = __fdiv_rn(__fmul_rn((float)(2*k1), 3.14159274101257324f), 196609.0f);
        c2b[j] = __fdiv_rn(__fmul_rn((float)(2*k2), 3.14159274101257324f), 196609.0f);
    }

    float a1R[4]={0,0,0,0}, a1I[4]={0,0,0,0};
    float a2R[4]={0,0,0,0}, a2I[4]={0,0,0,0};
    const int ph = lane + (lane >> 3);        // padded read base

    // z pipeline: lane-transposed layout, 2x dwordx4 per event; stride
    // between events = 512 floats = 128 float4.
    const float4* zp4 = (const float4*)(zf + (e0 + wave*8)*ASIZE + lane*8);
    float4 za = zp4[0], zb = zp4[1];

    for (int it = 0; it < 8; ++it) {
        const float sev = sF[e0 + wave*8 + it];   // wave-uniform scalar load
        // ---- stage 0 (st=1, p=lane): inputs z*T in registers
        {
            const float2 i0 = make_float2(za.x*T0.x, za.x*T0.y);
            const float2 i1 = make_float2(za.y*T1.x, za.y*T1.y);
            const float2 i2 = make_float2(za.z*T2.x, za.z*T2.y);
            const float2 i3 = make_float2(za.w*T3.x, za.w*T3.y);
            const float2 i4 = make_float2(zb.x*T4.x, zb.x*T4.y);
            const float2 i5 = make_float2(zb.y*T5.x, zb.y*T5.y);
            const float2 i6 = make_float2(zb.z*T6.x, zb.z*T6.y);
            const float2 i7 = make_float2(zb.w*T7.x, zb.w*T7.y);
            // prefetch next event's z (values consumed above). At it=7 this
            // reads 64B past zf, which is the (allocated) Ttab region — safe,
            // value unused.
            za = zp4[(it+1)*128];
            zb = zp4[(it+1)*128 + 1];
            float2 x0,x1,x2,x3,x4,x5,x6,x7;
            DFT8F(i0,i1,i2,i3,i4,i5,i6,i7, x0,x1,x2,x3,x4,x5,x6,x7);
            const int ob = 9*lane;                 // phys(8p+m) = 9p+m
            // twiddle powers as a depth-3 tree (slop-tolerant)
            const float2 W2 = cmulf(w0b, w0b);
            const float2 W3 = cmulf(W2, w0b);
            const float2 W4 = cmulf(W2, W2);
            F[ob]   = x0;
            F[ob+1] = cmulf(x1, w0b);
            F[ob+2] = cmulf(x2, W2);
            F[ob+3] = cmulf(x3, W3);
            F[ob+4] = cmulf(x4, W4);
            F[ob+5] = cmulf(x5, cmulf(W2, W3));
            F[ob+6] = cmulf(x6, cmulf(W3, W3));
            F[ob+7] = cmulf(x7, cmulf(W3, W4));
        }
        // ---- stage 1 (st=8): in-place (whole-wave reads precede writes)
        {
            const float2 i0 = F[ph      ], i1 = F[ph +  72], i2 = F[ph + 144],
                         i3 = F[ph + 216], i4 = F[ph + 288], i5 = F[ph + 360],
                         i6 = F[ph + 432], i7 = F[ph + 504];
            float2 x0,x1,x2,x3,x4,x5,x6,x7;
            DFT8F(i0,i1,i2,i3,i4,i5,i6,i7, x0,x1,x2,x3,x4,x5,x6,x7);
            const int q = lane & 7, p = lane >> 3;
            const int ob = q + 72*p;               // phys(q+64p+8m) = q+72p+9m
            const float2 V2 = cmulf(w1b, w1b);
            const float2 V3 = cmulf(V2, w1b);
            const float2 V4 = cmulf(V2, V2);
            F[ob]    = x0;
            F[ob+ 9] = cmulf(x1, w1b);
            F[ob+18] = cmulf(x2, V2);
            F[ob+27] = cmulf(x3, V3);
            F[ob+36] = cmulf(x4, V4);
            F[ob+45] = cmulf(x5, cmulf(V2, V3));
            F[ob+54] = cmulf(x6, cmulf(V3, V3));
            F[ob+63] = cmulf(x7, cmulf(V3, V4));
        }
        // ---- stage 2 (st=64, p=0): outputs in registers, Y[m] = bin(lane+64m)
        float2 Y[8];
        {
            const float2 i0 = F[ph      ], i1 = F[ph +  72], i2 = F[ph + 144],
                         i3 = F[ph + 216], i4 = F[ph + 288], i5 = F[ph + 360],
                         i6 = F[ph + 432], i7 = F[ph + 504];
            DFT8F(i0,i1,i2,i3,i4,i5,i6,i7, Y[0],Y[1],Y[2],Y[3],Y[4],Y[5],Y[6],Y[7]);
        }
        // ---- accumulate
        #pragma unroll
        for (int j = 0; j < 4; ++j) {
            float ps, pc;
            const float2 S0 = Y[j];
            phase_sc(__fmul_rn(c2a[j], sev), &ps, &pc);
            a1R[j] = fmaf(S0.x, pc, fmaf(-S0.y, ps, a1R[j]));
            a1I[j] = fmaf(S0.x, ps, fmaf( S0.y, pc, a1I[j]));
            const float2 S1 = Y[j+4];   // conj(S1) * e^{i theta}
            phase_sc(__fmul_rn(c2b[j], sev), &ps, &pc);
            a2R[j] = fmaf(S1.x, pc, fmaf( S1.y, ps, a2R[j]));
            a2I[j] = fmaf(S1.x, ps, fmaf(-S1.y, pc, a2I[j]));
        }
    }

    // ---- cross-wave reduction (2 rounds in the FFT region) + stores
    float* redF = (float*)FB;
    #pragma unroll
    for (int round = 0; round < 2; ++round) {
        __syncthreads();
        const int j0 = 2*round;
        float* my = redF + (wave*64 + lane)*8;
        my[0]=a1R[j0];   my[1]=a1I[j0];   my[2]=a2R[j0];   my[3]=a2I[j0];
        my[4]=a1R[j0+1]; my[5]=a1I[j0+1]; my[6]=a2R[j0+1]; my[7]=a2I[j0+1];
        __syncthreads();
        const int s = tid >> 2, c = tid & 3;
        #pragma unroll
        for (int jr = 0; jr < 2; ++jr) {
            float v = 0.f;
            #pragma unroll
            for (int w = 0; w < 4; ++w) v += redF[(w*64 + s)*8 + jr*4 + c];
            const int as = s + 64*(j0 + jr);
            if (c < 2) {
                Hqf[2*(quarter*196609 + b*256 + as) + c] = v;
            } else if (b != 384) {
                if (b != 0)
                    Hqf[2*(quarter*196609 + (768-b)*256 + (255-as)) + (c-2)] = v;
                else if (as == 0)
                    Hqf[2*(quarter*196609 + 196608) + (c-2)] = v;
            }
        }
    }
}

// ---------------------------------------------------------------------------
// inverse radix-4 Stockham stage over 256 points, 64 threads, f32, table
// twiddles (w = e^{+2pi i p*st/256} = Tw256f[p*st]; math verified R6-R8).
// ---------------------------------------------------------------------------
__device__ __forceinline__ void ifft256f_stage(
    const float2* __restrict__ src, float2* __restrict__ dst, int t, int s4,
    const float2* __restrict__ Tw256f)
{
    const int lg = 2*s4, st = 1 << lg;
    const int q = t & (st-1), p = t >> lg;
    const float2 A0 = src[t], A1 = src[t+64], A2 = src[t+128], A3 = src[t+192];
    const float Pr = A0.x + A2.x, Pi_ = A0.y + A2.y;
    const float Qr = A0.x - A2.x, Qi  = A0.y - A2.y;
    const float Rr = A1.x + A3.x, Ri  = A1.y + A3.y;
    const float Sr = A1.x - A3.x, Si  = A1.y - A3.y;
    const int tw = p*st;
    const float2 w1 = Tw256f[tw];
    const float2 w2 = Tw256f[(2*tw) & 255];
    const float2 w3 = Tw256f[(3*tw) & 255];
    const int o = q + 4*st*p;
    dst[o] = make_float2(Pr + Rr, Pi_ + Ri);
    const float u1r = Qr - Si, u1i = Qi + Sr;
    dst[o + st]   = make_float2(u1r*w1.x - u1i*w1.y, u1r*w1.y + u1i*w1.x);
    const float u2r = Pr - Rr, u2i = Pi_ - Ri;
    dst[o + 2*st] = make_float2(u2r*w2.x - u2i*w2.y, u2r*w2.y + u2i*w2.x);
    const float u3r = Qr + Si, u3i = Qi - Sr;
    dst[o + 3*st] = make_float2(u3r*w3.x - u3i*w3.y, u3r*w3.y + u3i*w3.x);
}

// ---------------------------------------------------------------------------
// K4: inverse four-step, stage A. ONE single-wave block per job (l, j1):
// sum 4 quarter-partials of H at k = 3j1+l+768j2 (+ Hermitian partner),
// pack G inline, f32 FFT-256 over j2, four-step twiddle, TRANSPOSED store
// Yg[m1*768 + job] (coalesced reads in stage B). No barriers (1 wave).
// k0 twiddle from Tk table (bit-identical values, no per-thread fp64 sincos).
// ---------------------------------------------------------------------------
__global__ __launch_bounds__(64) void inv_a(
    const float* __restrict__ Hqf, const float2* __restrict__ Twf,
    const float2* __restrict__ Tk, float2* __restrict__ Yg)
{
    __shared__ float2 buf[512];
    const int t = threadIdx.x;
    const int job = blockIdx.x;                 // 0..767
    const int l = job >> 8, j1 = job & 255;
    const int k0 = 3*j1 + l;
    float2* A = buf; float2* B = buf + 256;
    const float2* Hq2 = (const float2*)Hqf;
    const float2* Tw256f = Twf;
    const float2* Tw512f = Twf + 256;
    const float2* Tw64kf = Twf + 768;

    const float2 tkv = Tk[k0];                  // e^{2pi i k0/NFFT}
    const float Scf = tkv.x, Ssf = tkv.y;

    #pragma unroll
    for (int r = 0; r < 4; ++r) {
        const int j2 = t + 64*r;
        const int idxK = k0*256 + j2;
        int idxM;
        if (k0 > 0) idxM = (768 - k0)*256 + (255 - j2);
        else        idxM = (j2 == 0) ? 196608 : (256 - j2);
        float hkR=0.f, hkI=0.f, hmR=0.f, hmI=0.f;
        #pragma unroll
        for (int q = 0; q < 4; ++q) {
            const float2 vk = Hq2[q*196609 + idxK];
            const float2 vm = Hq2[q*196609 + idxM];
            hkR += vk.x; hkI += vk.y;
            hmR += vm.x; hmI += vm.y;
        }
        if (k0 == 0 && j2 == 0) { hkI = 0.f; hmI = 0.f; }  // irfft Im-drop
        const float Pr = hkR + hmR, Pi_ = hkI - hmI;
        const float Qr = hkR - hmR, Qi = hkI + hmI;
        const float2 t5 = Tw512f[j2];                  // e^{2pi i j2/512}
        const float Wc = Scf*t5.x - Ssf*t5.y;          // e^{2pi i k/NFFT}
        const float Wsn = Scf*t5.y + Ssf*t5.x;
        const float WQr = Wc*Qr - Wsn*Qi;
        const float WQi = Wc*Qi + Wsn*Qr;
        A[j2] = make_float2(0.5f*(Pr - WQi), 0.5f*(Pi_ + WQr));
    }

    ifft256f_stage(A, B, t, 0, Tw256f);
    ifft256f_stage(B, A, t, 1, Tw256f);
    ifft256f_stage(A, B, t, 2, Tw256f);
    ifft256f_stage(B, A, t, 3, Tw256f);

    #pragma unroll
    for (int r = 0; r < 4; ++r) {
        const int m1 = t + 64*r;
        const float2 v = A[m1];
        const int vv = j1*m1;
        const float2 wa = Tw256f[vv >> 8];
        const float2 wb = Tw64kf[vv & 255];
        const float twc = wa.x*wb.x - wa.y*wb.y;
        const float tws = wa.x*wb.y + wa.y*wb.x;
        Yg[m1*768 + job] = make_float2(v.x*twc - v.y*tws, v.x*tws + v.y*twc);
    }
}

// ---------------------------------------------------------------------------
// K5: inverse four-step, stage B + radix-3 combine + 1/M + f32 output.
// Block per m1, 192 threads = 3 single-wave FFT jobs (l = 0..2), then combine.
// m1 twiddle from Tm table (bit-identical values).
// ---------------------------------------------------------------------------
__global__ __launch_bounds__(192) void inv_b(
    const float2* __restrict__ Yg, const float2* __restrict__ Twf,
    const float2* __restrict__ Tm, float* __restrict__ out)
{
    __shared__ float2 buf[3*512];
    const int m1 = blockIdx.x;
    const int tid = threadIdx.x;
    const int l = tid >> 6, t = tid & 63;
    const float2* Tw256f = Twf;
    const float2* Tw768f = Twf + 512;
    {
        float2* A = buf + l*512;
        float2* B = A + 256;
        #pragma unroll
        for (int r = 0; r < 4; ++r) {
            const int j1 = t + 64*r;
            A[j1] = Yg[m1*768 + l*256 + j1];      // coalesced
        }
        ifft256f_stage(A, B, t, 0, Tw256f);
        ifft256f_stage(B, A, t, 1, Tw256f);
        ifft256f_stage(A, B, t, 2, Tw256f);
        ifft256f_stage(B, A, t, 3, Tw256f);
    }
    __syncthreads();

    const float2 tmv = Tm[m1];                    // e^{2pi i m1/MHALF}
    const float cm = tmv.x, sm = tmv.y;
    const float inv = 1.0f/(float)MHALF;
    for (int m2 = tid; m2 < 256; m2 += 192) {
        const float2 F0 = buf[m2];
        const float2 F1 = buf[512 + m2];
        const float2 F2 = buf[1024 + m2];
        const float2 t7 = Tw768f[m2];                 // e^{2pi i m2/768}
        const float w1c = cm*t7.x - sm*t7.y, w1s = cm*t7.y + sm*t7.x;
        const float w2c = w1c*w1c - w1s*w1s, w2s = 2.0f*w1c*w1s;
        const float gr = F0.x + (w1c*F1.x - w1s*F1.y) + (w2c*F2.x - w2s*F2.y);
        const float gi = F0.y + (w1c*F1.y + w1s*F1.x) + (w2c*F2.y + w2s*F2.x);
        const int m = m1 + 256*m2;
        out[2*m]     = gr*inv;
        out[2*m + 1] = gi*inv;
    }
}

// ---------------------------------------------------------------------------
extern "C" void kernel_launch(void* const* d_in, const int* in_sizes, int n_in,
                              void* d_out, int out_size, void* d_ws, size_t ws_size,
                              hipStream_t stream) {
    const float* base       = (const float*)d_in[0];
    const float* to_off_w   = (const float*)d_in[1];
    const float* split_w    = (const float*)d_in[2];
    const float* split_b    = (const float*)d_in[3];
    const float* atoms      = (const float*)d_in[4];
    const float* to_atoms_w = (const float*)d_in[5];
    const float* to_atoms_b = (const float*)d_in[6];
    const float* to_amp_w   = (const float*)d_in[7];
    const float* to_amp_b   = (const float*)d_in[8];
    float* out = (float*)d_out;

    // workspace layout: 8,147,488 B (< 9,715,728 proven-safe in R4).
    // Yg aliases Ttab: forward (last Ttab reader) completes before inv_a.
    // Tk/Tm live in the old xF slot [8704, 16896).
    // NOTE: forward_v3's z-prefetch at it=7 reads 64B past zf, landing in
    // Ttab — allocated memory, value unused.
    char* ws = (char*)d_ws;
    float2* Twf  = (float2*)(ws + 0);          // 4*256*8 = 8192
    float*  sF   = (float*)(ws + 8192);        //   512
    float2* Tk   = (float2*)(ws + 8704);       // 768*8 = 6144 -> 14848
    float2* Tm   = (float2*)(ws + 14848);      // 256*8 = 2048 -> 16896
    float*  zf   = (float*)(ws + 16896);       // 262144 -> 279040
    float2* Ttab = (float2*)(ws + 279040);     // 385*512*8 = 1576960 -> 1856000
    float2* Yg   = (float2*)(ws + 279040);     // 768*256*8 = 1572864 (alias)
    float*  Hqf  = (float*)(ws + 1856000);     // 4*196609*8 = 6291488 -> 8147488

    init_events<<<514, 256, 0, stream>>>(base, to_off_w, split_w, split_b,
                                         atoms, to_atoms_w, to_atoms_b,
                                         to_amp_w, to_amp_b,
                                         sF, Twf, Ttab, Tk, Tm, zf);
    forward_v3<<<385*4, 256, 0, stream>>>(zf, sF, Ttab, Hqf);
    inv_a<<<768, 64, 0, stream>>>(Hqf, Twf, Tk, Yg);
    inv_b<<<256, 192, 0, stream>>>(Yg, Twf, Tm, out);
}